// Round 1
// baseline (2369.219 us; speedup 1.0000x reference)
//
#include <hip/hip_runtime.h>
#include <stdint.h>

// GemNet OutputBlock fused kernels for MI355X (gfx950).
// E = MLP(segment_sum(m .* (rbf@We_rbf))) @ We_out
// F = (ResMLP(ssilu(m@Wf_in)) .* (rbf@Wf_rbf)) @ Wf_out
// All GEMMs via v_mfma_f32_16x16x32_bf16, f32 accumulation.

typedef __attribute__((ext_vector_type(8))) short bf16x8;
typedef __attribute__((ext_vector_type(4))) float f32x4;

#define INV_SQRT2 0.7071067811865476f

// ---- workspace layout (bytes) ----
#define XE_OFF     0ull
#define XE_BYTES   25600000ull                 // xE f32 [25000][256]
#define FWT_OFF    (XE_OFF + XE_BYTES)
#define FWT_BYTES  917504ull                   // 7 x [256][256] bf16, transposed+swizzled
#define EWT0_OFF   (FWT_OFF + FWT_BYTES)
#define EWT0_BYTES 65536ull                    // [128][256] bf16
#define EWTR_OFF   (EWT0_OFF + EWT0_BYTES)
#define EWTR_BYTES 196608ull                   // 6 x [128][128] bf16
#define W2F_OFF    (EWTR_OFF + EWTR_BYTES)
#define W2F_BYTES  16384ull                    // (Wf_rbf .* Wf_out)^T [256][32] bf16 (k padded)
#define W2E_OFF    (W2F_OFF + W2F_BYTES)
#define W2E_BYTES  16384ull                    // We_rbf^T [256][32] bf16 (k padded)

static __device__ __forceinline__ unsigned short f2bf(float f) {
  union { float f; unsigned u; } v; v.f = f;
  return (unsigned short)((v.u + 0x7fffu + ((v.u >> 16) & 1u)) >> 16);
}
static __device__ __forceinline__ float bf2f(unsigned short h) {
  union { unsigned u; float f; } v; v.u = ((unsigned)h) << 16;
  return v.f;
}
static __device__ __forceinline__ float ssilu(float x) {
  // silu(x)/0.6 = x * sigmoid(x) * 5/3
  return 1.6666666666666667f * x * __builtin_amdgcn_rcpf(1.0f + __expf(-x));
}
static __device__ __forceinline__ void gl16(const void* g, void* l) {
  // async global->LDS, 16B per lane; LDS dest is wave-uniform base + lane*16
  __builtin_amdgcn_global_load_lds(
      (const __attribute__((address_space(1))) void*)(unsigned long long)(uintptr_t)g,
      (__attribute__((address_space(3))) void*)(unsigned)(uintptr_t)l, 16, 0, 0);
}

// =====================================================================
// prep: weights f32 -> bf16, transposed to [out][in], XOR-swizzled so that
// LDS-linear staging via global_load_lds yields bank-conflict-free B reads.
// =====================================================================
__global__ void prep_kernel(const float* __restrict__ We_rbf,
                            const float* __restrict__ We_in,
                            const float* __restrict__ We_res,
                            const float* __restrict__ Wf_rbf,
                            const float* __restrict__ Wf_in,
                            const float* __restrict__ Wf_res,
                            const float* __restrict__ Wf_out,
                            char* __restrict__ ws) {
  int idx = blockIdx.x * 256 + threadIdx.x;
  if (idx < 458752) {  // FWt: 7 stages [k=256][c=256] -> [c][k]
    int s = idx >> 16, r = idx & 65535, k = r >> 8, c = r & 255;
    float v = (s == 0) ? Wf_in[k * 256 + c] : Wf_res[(s - 1) * 65536 + k * 256 + c];
    *(unsigned short*)(ws + FWT_OFF + (unsigned long long)s * 131072 +
                       c * 512 + ((k * 2) ^ ((c & 7) << 4))) = f2bf(v);
    return;
  }
  idx -= 458752;
  if (idx < 32768) {  // EWt0: [k=256][c=128] -> [c][k]
    int k = idx >> 7, c = idx & 127;
    *(unsigned short*)(ws + EWT0_OFF + c * 512 + ((k * 2) ^ ((c & 7) << 4))) = f2bf(We_in[k * 128 + c]);
    return;
  }
  idx -= 32768;
  if (idx < 98304) {  // EWtR: 6 stages [k=128][c=128] -> [c][k]
    int s = idx >> 14, r = idx & 16383, k = r >> 7, c = r & 127;
    *(unsigned short*)(ws + EWTR_OFF + (unsigned long long)s * 32768 +
                       c * 256 + ((k * 2) ^ ((c & 7) << 4))) = f2bf(We_res[s * 16384 + k * 128 + c]);
    return;
  }
  idx -= 98304;
  if (idx < 8192) {  // W2F: (Wf_rbf[k][c]*Wf_out[c])^T, k padded 16->32
    int c = idx >> 5, k = idx & 31;
    float v = (k < 16) ? Wf_rbf[k * 256 + c] * Wf_out[c] : 0.f;
    *(unsigned short*)(ws + W2F_OFF + c * 64 + ((k * 2) ^ ((c & 3) << 4))) = f2bf(v);
    return;
  }
  idx -= 8192;
  if (idx < 8192) {  // W2E: We_rbf^T, k padded
    int c = idx >> 5, k = idx & 31;
    float v = (k < 16) ? We_rbf[k * 256 + c] : 0.f;
    *(unsigned short*)(ws + W2E_OFF + c * 64 + ((k * 2) ^ ((c & 3) << 4))) = f2bf(v);
  }
}

// =====================================================================
// scatter: xE[id_j[e]] += m[e] .* (rbf[e] @ We_rbf)   (f32 atomics)
// 128 edges / block; rbf@We_rbf via MFMA (K=16 padded to 32).
// =====================================================================
__global__ __launch_bounds__(256) void scatter_kernel(
    const float* __restrict__ m, const float* __restrict__ rbf,
    const int* __restrict__ id_j, const char* __restrict__ W2E,
    float* __restrict__ xE, int nE) {
  __shared__ char rbfA[8192];   // [128][32] bf16, swizzled (row&3)<<4
  __shared__ char wb[16384];    // W2E staged
  __shared__ int sI[128];
  const int tid = threadIdx.x;
  const int lane = tid & 63, q = lane >> 4, r15 = lane & 15;
  const int wid = tid >> 6, wrow = wid * 32;
  const long long row0 = (long long)blockIdx.x * 128;
  const f32x4 zf = {0.f, 0.f, 0.f, 0.f};

#pragma unroll
  for (int i = 0; i < 8; ++i) {
    const int idx = tid * 8 + i;
    const int row = idx >> 4, d = idx & 15;
    long long rg = row0 + row; if (rg >= nE) rg = nE - 1;
    *(unsigned short*)(rbfA + row * 64 + ((d * 2) ^ ((row & 3) << 4))) = f2bf(rbf[rg * 16 + d]);
    *(unsigned short*)(rbfA + row * 64 + (((16 + d) * 2) ^ ((row & 3) << 4))) = 0;
  }
  if (tid < 128) {
    long long rg = row0 + tid;
    sI[tid] = (rg < nE) ? id_j[rg] : -1;
  }
#pragma unroll
  for (int i = 0; i < 4; ++i) gl16(W2E + i * 4096 + tid * 16, wb + i * 4096 + tid * 16);
  asm volatile("s_waitcnt vmcnt(0)" ::: "memory");
  __syncthreads();

  bf16x8 ar[2];
#pragma unroll
  for (int fr = 0; fr < 2; ++fr) {
    const int row = wrow + fr * 16 + r15;
    ar[fr] = *(const bf16x8*)(rbfA + row * 64 + ((q * 16) ^ ((row & 3) << 4)));
  }
#pragma unroll
  for (int fcg = 0; fcg < 16; ++fcg) {
    const int ci = fcg * 16 + r15;
    bf16x8 bw = *(const bf16x8*)(wb + ci * 64 + ((q * 16) ^ ((ci & 3) << 4)));
#pragma unroll
    for (int fr = 0; fr < 2; ++fr) {
      f32x4 rw = __builtin_amdgcn_mfma_f32_16x16x32_bf16(ar[fr], bw, zf, 0, 0, 0);
      const int col = fcg * 16 + r15;
#pragma unroll
      for (int j = 0; j < 4; ++j) {
        const int rowl = wrow + fr * 16 + q * 4 + j;
        const int aid = sI[rowl];
        if (aid >= 0) {
          const long long rg = row0 + rowl;
          float mv = m[rg * 256 + col];
          atomicAdd(&xE[(long long)aid * 256 + col], mv * rw[j]);
        }
      }
    }
  }
}

// =====================================================================
// force: fully fused 7-GEMM chain over [nE][256] + rbf gating + Wf_out dot
// 128 rows/block, 4 waves x 32 rows. A frags in regs; X round-trips a
// single 64KB swizzled LDS buffer; residual stream packed-bf16 in regs.
// =====================================================================
__global__ __launch_bounds__(256, 2) void force_kernel(
    const float* __restrict__ m, const float* __restrict__ rbf,
    const char* __restrict__ FWt, const char* __restrict__ W2F,
    float* __restrict__ Fout, int nE) {
  __shared__ char xbuf[65536];  // [128][256] bf16, rows 512B, swz (row&7)<<4
  __shared__ char wbuf[16384];  // one 32-col weight chunk
  const int tid = threadIdx.x;
  const int lane = tid & 63, q = lane >> 4, r15 = lane & 15;
  const int wid = tid >> 6, wrow = wid * 32;
  const long long row0 = (long long)blockIdx.x * 128;
  const f32x4 zf = {0.f, 0.f, 0.f, 0.f};

  bf16x8 a[2][8];
  unsigned xs[8][2][2][2];  // residual stream x, packed 2xbf16, lane's D positions

  // stage-0 A frags from m (f32 -> bf16)
#pragma unroll
  for (int fr = 0; fr < 2; ++fr) {
#pragma unroll
    for (int ks = 0; ks < 8; ++ks) {
      long long rg = row0 + wrow + fr * 16 + r15; if (rg >= nE) rg = nE - 1;
      const float* p = m + rg * 256 + ks * 32 + q * 8;
      float4 v0 = *(const float4*)p;
      float4 v1 = *(const float4*)(p + 4);
      bf16x8 t;
      t[0] = (short)f2bf(v0.x); t[1] = (short)f2bf(v0.y);
      t[2] = (short)f2bf(v0.z); t[3] = (short)f2bf(v0.w);
      t[4] = (short)f2bf(v1.x); t[5] = (short)f2bf(v1.y);
      t[6] = (short)f2bf(v1.z); t[7] = (short)f2bf(v1.w);
      a[fr][ks] = t;
    }
  }

  for (int s = 0; s < 7; ++s) {
    const char* wsrc = FWt + (unsigned long long)s * 131072;
    const int isS0 = (s == 0);
    const int isRes = (s >= 2) && ((s & 1) == 0);
#pragma unroll
    for (int c = 0; c < 8; ++c) {
#pragma unroll
      for (int i = 0; i < 4; ++i)
        gl16(wsrc + c * 16384 + i * 4096 + tid * 16, wbuf + i * 4096 + tid * 16);
      asm volatile("s_waitcnt vmcnt(0)" ::: "memory");
      __syncthreads();

      f32x4 acc[2][2] = {{zf, zf}, {zf, zf}};
#pragma unroll
      for (int ks = 0; ks < 8; ++ks) {
        const int kb = (ks * 32 + q * 8) * 2;
        const int ci0 = r15, ci1 = 16 + r15;
        bf16x8 b0 = *(const bf16x8*)(wbuf + ci0 * 512 + (kb ^ ((ci0 & 7) << 4)));
        bf16x8 b1 = *(const bf16x8*)(wbuf + ci1 * 512 + (kb ^ ((ci1 & 7) << 4)));
        acc[0][0] = __builtin_amdgcn_mfma_f32_16x16x32_bf16(a[0][ks], b0, acc[0][0], 0, 0, 0);
        acc[1][0] = __builtin_amdgcn_mfma_f32_16x16x32_bf16(a[1][ks], b0, acc[1][0], 0, 0, 0);
        acc[0][1] = __builtin_amdgcn_mfma_f32_16x16x32_bf16(a[0][ks], b1, acc[0][1], 0, 0, 0);
        acc[1][1] = __builtin_amdgcn_mfma_f32_16x16x32_bf16(a[1][ks], b1, acc[1][1], 0, 0, 0);
      }
#pragma unroll
      for (int fr = 0; fr < 2; ++fr) {
#pragma unroll
        for (int fc = 0; fc < 2; ++fc) {
          float o0 = ssilu(acc[fr][fc][0]), o1 = ssilu(acc[fr][fc][1]);
          float o2 = ssilu(acc[fr][fc][2]), o3 = ssilu(acc[fr][fc][3]);
          if (isRes) {
            const unsigned p0 = xs[c][fr][fc][0], p1 = xs[c][fr][fc][1];
            o0 = (bf2f((unsigned short)(p0 & 0xffff)) + o0) * INV_SQRT2;
            o1 = (bf2f((unsigned short)(p0 >> 16)) + o1) * INV_SQRT2;
            o2 = (bf2f((unsigned short)(p1 & 0xffff)) + o2) * INV_SQRT2;
            o3 = (bf2f((unsigned short)(p1 >> 16)) + o3) * INV_SQRT2;
          }
          const unsigned short h0 = f2bf(o0), h1 = f2bf(o1), h2 = f2bf(o2), h3 = f2bf(o3);
          if (isS0 | isRes) {
            xs[c][fr][fc][0] = (unsigned)h0 | ((unsigned)h1 << 16);
            xs[c][fr][fc][1] = (unsigned)h2 | ((unsigned)h3 << 16);
          }
          if (s < 6) {
            const int colb = (c * 32 + fc * 16 + r15) * 2;
            const int rb = wrow + fr * 16 + q * 4;
            *(unsigned short*)(xbuf + (rb + 0) * 512 + (colb ^ (((rb + 0) & 7) << 4))) = h0;
            *(unsigned short*)(xbuf + (rb + 1) * 512 + (colb ^ (((rb + 1) & 7) << 4))) = h1;
            *(unsigned short*)(xbuf + (rb + 2) * 512 + (colb ^ (((rb + 2) & 7) << 4))) = h2;
            *(unsigned short*)(xbuf + (rb + 3) * 512 + (colb ^ (((rb + 3) & 7) << 4))) = h3;
          }
        }
      }
      __syncthreads();
    }
    if (s < 6) {  // reload A frags for next stage (chunk-0 barrier of next stage protects)
#pragma unroll
      for (int fr = 0; fr < 2; ++fr) {
#pragma unroll
        for (int ks = 0; ks < 8; ++ks) {
          const int row = wrow + fr * 16 + r15;
          const int kb = (ks * 32 + q * 8) * 2;
          a[fr][ks] = *(const bf16x8*)(xbuf + row * 512 + (kb ^ ((row & 7) << 4)));
        }
      }
    }
  }

  // ---- final: rbfw = rbf @ (Wf_rbf .* Wf_out);  F = sum_c x .* rbfw ----
#pragma unroll
  for (int i = 0; i < 8; ++i) {
    const int idx = tid * 8 + i;
    const int row = idx >> 4, d = idx & 15;
    long long rg = row0 + row; if (rg >= nE) rg = nE - 1;
    *(unsigned short*)(xbuf + row * 64 + ((d * 2) ^ ((row & 3) << 4))) = f2bf(rbf[rg * 16 + d]);
    *(unsigned short*)(xbuf + row * 64 + (((16 + d) * 2) ^ ((row & 3) << 4))) = 0;
  }
#pragma unroll
  for (int i = 0; i < 4; ++i) gl16(W2F + i * 4096 + tid * 16, wbuf + i * 4096 + tid * 16);
  asm volatile("s_waitcnt vmcnt(0)" ::: "memory");
  __syncthreads();

  bf16x8 ar[2];
#pragma unroll
  for (int fr = 0; fr < 2; ++fr) {
    const int row = wrow + fr * 16 + r15;
    ar[fr] = *(const bf16x8*)(xbuf + row * 64 + ((q * 16) ^ ((row & 3) << 4)));
  }
  float psum[2][4] = {{0.f, 0.f, 0.f, 0.f}, {0.f, 0.f, 0.f, 0.f}};
#pragma unroll
  for (int fcg = 0; fcg < 16; ++fcg) {
    const int ci = fcg * 16 + r15;
    bf16x8 bw = *(const bf16x8*)(wbuf + ci * 64 + ((q * 16) ^ ((ci & 3) << 4)));
#pragma unroll
    for (int fr = 0; fr < 2; ++fr) {
      f32x4 rw = __builtin_amdgcn_mfma_f32_16x16x32_bf16(ar[fr], bw, zf, 0, 0, 0);
      const unsigned p0 = xs[fcg >> 1][fr][fcg & 1][0];
      const unsigned p1 = xs[fcg >> 1][fr][fcg & 1][1];
      psum[fr][0] += bf2f((unsigned short)(p0 & 0xffff)) * rw[0];
      psum[fr][1] += bf2f((unsigned short)(p0 >> 16)) * rw[1];
      psum[fr][2] += bf2f((unsigned short)(p1 & 0xffff)) * rw[2];
      psum[fr][3] += bf2f((unsigned short)(p1 >> 16)) * rw[3];
    }
  }
#pragma unroll
  for (int off = 1; off < 16; off <<= 1) {
#pragma unroll
    for (int fr = 0; fr < 2; ++fr) {
#pragma unroll
      for (int j = 0; j < 4; ++j) psum[fr][j] += __shfl_xor(psum[fr][j], off, 64);
    }
  }
  if (r15 == 0) {
#pragma unroll
    for (int fr = 0; fr < 2; ++fr) {
#pragma unroll
      for (int j = 0; j < 4; ++j) {
        const long long rg = row0 + wrow + fr * 16 + q * 4 + j;
        if (rg < nE) Fout[rg] = psum[fr][j];
      }
    }
  }
}

// =====================================================================
// energy MLP: xE[25000][256] -> ssilu(@We_in[256x128]) -> 3 residual(128) -> @We_out
// =====================================================================
__global__ __launch_bounds__(256, 2) void energy_kernel(
    const float* __restrict__ xE, const char* __restrict__ EWt0,
    const char* __restrict__ EWtR, const float* __restrict__ We_out,
    float* __restrict__ Eout, int nA) {
  __shared__ char xbuf[32768];  // [128][128] bf16, rows 256B
  __shared__ char wbuf[16384];
  const int tid = threadIdx.x;
  const int lane = tid & 63, q = lane >> 4, r15 = lane & 15;
  const int wid = tid >> 6, wrow = wid * 32;
  const long long row0 = (long long)blockIdx.x * 128;
  const f32x4 zf = {0.f, 0.f, 0.f, 0.f};

  bf16x8 a[2][8];
  unsigned xs[4][2][2][2];

#pragma unroll
  for (int fr = 0; fr < 2; ++fr) {
#pragma unroll
    for (int ks = 0; ks < 8; ++ks) {
      long long rg = row0 + wrow + fr * 16 + r15;
      bf16x8 t = {0, 0, 0, 0, 0, 0, 0, 0};
      if (rg < nA) {
        const float* p = xE + rg * 256 + ks * 32 + q * 8;
        float4 v0 = *(const float4*)p;
        float4 v1 = *(const float4*)(p + 4);
        t[0] = (short)f2bf(v0.x); t[1] = (short)f2bf(v0.y);
        t[2] = (short)f2bf(v0.z); t[3] = (short)f2bf(v0.w);
        t[4] = (short)f2bf(v1.x); t[5] = (short)f2bf(v1.y);
        t[6] = (short)f2bf(v1.z); t[7] = (short)f2bf(v1.w);
      }
      a[fr][ks] = t;
    }
  }

  for (int s = 0; s < 7; ++s) {
    const int K2 = (s == 0) ? 512 : 256;  // bytes per weight row
    const int wchunk = 32 * K2;
    const int nld = wchunk >> 12;         // 4 or 2 16B-loads per thread
    const char* wsrc = (s == 0) ? EWt0 : (EWtR + (unsigned long long)(s - 1) * 32768);
    const int isS0 = (s == 0);
    const int isRes = (s >= 2) && ((s & 1) == 0);
#pragma unroll
    for (int c = 0; c < 4; ++c) {
      for (int i = 0; i < nld; ++i)
        gl16(wsrc + c * wchunk + i * 4096 + tid * 16, wbuf + i * 4096 + tid * 16);
      asm volatile("s_waitcnt vmcnt(0)" ::: "memory");
      __syncthreads();

      f32x4 acc[2][2] = {{zf, zf}, {zf, zf}};
      if (s == 0) {
#pragma unroll
        for (int ks = 0; ks < 8; ++ks) {
          const int kb = (ks * 32 + q * 8) * 2;
          const int ci0 = r15, ci1 = 16 + r15;
          bf16x8 b0 = *(const bf16x8*)(wbuf + ci0 * 512 + (kb ^ ((ci0 & 7) << 4)));
          bf16x8 b1 = *(const bf16x8*)(wbuf + ci1 * 512 + (kb ^ ((ci1 & 7) << 4)));
          acc[0][0] = __builtin_amdgcn_mfma_f32_16x16x32_bf16(a[0][ks], b0, acc[0][0], 0, 0, 0);
          acc[1][0] = __builtin_amdgcn_mfma_f32_16x16x32_bf16(a[1][ks], b0, acc[1][0], 0, 0, 0);
          acc[0][1] = __builtin_amdgcn_mfma_f32_16x16x32_bf16(a[0][ks], b1, acc[0][1], 0, 0, 0);
          acc[1][1] = __builtin_amdgcn_mfma_f32_16x16x32_bf16(a[1][ks], b1, acc[1][1], 0, 0, 0);
        }
      } else {
#pragma unroll
        for (int ks = 0; ks < 4; ++ks) {
          const int kb = (ks * 32 + q * 8) * 2;
          const int ci0 = r15, ci1 = 16 + r15;
          bf16x8 b0 = *(const bf16x8*)(wbuf + ci0 * 256 + (kb ^ ((ci0 & 7) << 4)));
          bf16x8 b1 = *(const bf16x8*)(wbuf + ci1 * 256 + (kb ^ ((ci1 & 7) << 4)));
          acc[0][0] = __builtin_amdgcn_mfma_f32_16x16x32_bf16(a[0][ks], b0, acc[0][0], 0, 0, 0);
          acc[1][0] = __builtin_amdgcn_mfma_f32_16x16x32_bf16(a[1][ks], b0, acc[1][0], 0, 0, 0);
          acc[0][1] = __builtin_amdgcn_mfma_f32_16x16x32_bf16(a[0][ks], b1, acc[0][1], 0, 0, 0);
          acc[1][1] = __builtin_amdgcn_mfma_f32_16x16x32_bf16(a[1][ks], b1, acc[1][1], 0, 0, 0);
        }
      }
#pragma unroll
      for (int fr = 0; fr < 2; ++fr) {
#pragma unroll
        for (int fc = 0; fc < 2; ++fc) {
          float o0 = ssilu(acc[fr][fc][0]), o1 = ssilu(acc[fr][fc][1]);
          float o2 = ssilu(acc[fr][fc][2]), o3 = ssilu(acc[fr][fc][3]);
          if (isRes) {
            const unsigned p0 = xs[c][fr][fc][0], p1 = xs[c][fr][fc][1];
            o0 = (bf2f((unsigned short)(p0 & 0xffff)) + o0) * INV_SQRT2;
            o1 = (bf2f((unsigned short)(p0 >> 16)) + o1) * INV_SQRT2;
            o2 = (bf2f((unsigned short)(p1 & 0xffff)) + o2) * INV_SQRT2;
            o3 = (bf2f((unsigned short)(p1 >> 16)) + o3) * INV_SQRT2;
          }
          const unsigned short h0 = f2bf(o0), h1 = f2bf(o1), h2 = f2bf(o2), h3 = f2bf(o3);
          if (isS0 | isRes) {
            xs[c][fr][fc][0] = (unsigned)h0 | ((unsigned)h1 << 16);
            xs[c][fr][fc][1] = (unsigned)h2 | ((unsigned)h3 << 16);
          }
          if (s < 6) {
            const int colb = (c * 32 + fc * 16 + r15) * 2;
            const int rb = wrow + fr * 16 + q * 4;
            *(unsigned short*)(xbuf + (rb + 0) * 256 + (colb ^ (((rb + 0) & 7) << 4))) = h0;
            *(unsigned short*)(xbuf + (rb + 1) * 256 + (colb ^ (((rb + 1) & 7) << 4))) = h1;
            *(unsigned short*)(xbuf + (rb + 2) * 256 + (colb ^ (((rb + 2) & 7) << 4))) = h2;
            *(unsigned short*)(xbuf + (rb + 3) * 256 + (colb ^ (((rb + 3) & 7) << 4))) = h3;
          }
        }
      }
      __syncthreads();
    }
    if (s < 6) {
#pragma unroll
      for (int fr = 0; fr < 2; ++fr) {
#pragma unroll
        for (int ks = 0; ks < 4; ++ks) {
          const int row = wrow + fr * 16 + r15;
          const int kb = (ks * 32 + q * 8) * 2;
          a[fr][ks] = *(const bf16x8*)(xbuf + row * 256 + (kb ^ ((row & 7) << 4)));
        }
      }
    }
  }

  // final: E[row] = sum_c x[row,c] * We_out[c]
  float psum[2][4] = {{0.f, 0.f, 0.f, 0.f}, {0.f, 0.f, 0.f, 0.f}};
#pragma unroll
  for (int c = 0; c < 4; ++c) {
#pragma unroll
    for (int f = 0; f < 2; ++f) {
      const int col = c * 32 + f * 16 + r15;
      const float wo = We_out[col];
#pragma unroll
      for (int fr = 0; fr < 2; ++fr) {
        const unsigned p0 = xs[c][fr][f][0], p1 = xs[c][fr][f][1];
        psum[fr][0] += bf2f((unsigned short)(p0 & 0xffff)) * wo;
        psum[fr][1] += bf2f((unsigned short)(p0 >> 16)) * wo;
        psum[fr][2] += bf2f((unsigned short)(p1 & 0xffff)) * wo;
        psum[fr][3] += bf2f((unsigned short)(p1 >> 16)) * wo;
      }
    }
  }
#pragma unroll
  for (int off = 1; off < 16; off <<= 1) {
#pragma unroll
    for (int fr = 0; fr < 2; ++fr) {
#pragma unroll
      for (int j = 0; j < 4; ++j) psum[fr][j] += __shfl_xor(psum[fr][j], off, 64);
    }
  }
  if (r15 == 0) {
#pragma unroll
    for (int fr = 0; fr < 2; ++fr) {
#pragma unroll
      for (int j = 0; j < 4; ++j) {
        const long long rg = row0 + wrow + fr * 16 + q * 4 + j;
        if (rg < nA) Eout[rg] = psum[fr][j];
      }
    }
  }
}

// =====================================================================
extern "C" void kernel_launch(void* const* d_in, const int* in_sizes, int n_in,
                              void* d_out, int out_size, void* d_ws, size_t ws_size,
                              hipStream_t stream) {
  const float* m      = (const float*)d_in[1];
  const float* rbf    = (const float*)d_in[2];
  const int*   id_j   = (const int*)d_in[3];
  const float* We_rbf = (const float*)d_in[4];
  const float* We_in  = (const float*)d_in[5];
  const float* We_res = (const float*)d_in[6];
  const float* We_out = (const float*)d_in[7];
  const float* Wf_rbf = (const float*)d_in[8];
  const float* Wf_in  = (const float*)d_in[9];
  const float* Wf_res = (const float*)d_in[10];
  const float* Wf_out = (const float*)d_in[11];
  const int nA = in_sizes[0] / 128;   // 25000
  const int nE = in_sizes[1] / 256;   // 400000

  char* ws = (char*)d_ws;
  float* xE = (float*)(ws + XE_OFF);
  float* Eout = (float*)d_out;
  float* Fout = Eout + nA;

  prep_kernel<<<2368, 256, 0, stream>>>(We_rbf, We_in, We_res, Wf_rbf, Wf_in, Wf_res, Wf_out, ws);
  hipMemsetAsync(xE, 0, (size_t)nA * 256 * 4, stream);
  scatter_kernel<<<(nE + 127) / 128, 256, 0, stream>>>(m, rbf, id_j, ws + W2E_OFF, xE, nE);
  energy_kernel<<<(nA + 127) / 128, 256, 0, stream>>>(xE, ws + EWT0_OFF, ws + EWTR_OFF, We_out, Eout, nA);
  force_kernel<<<(nE + 127) / 128, 256, 0, stream>>>(m, rbf, ws + FWT_OFF, ws + W2F_OFF, Fout, nE);
}

// Round 2
// 1508.322 us; speedup vs baseline: 1.5708x; 1.5708x over previous
//
#include <hip/hip_runtime.h>
#include <stdint.h>

// GemNet OutputBlock fused kernels for MI355X (gfx950).
// E = MLP(segment_sum(m .* (rbf@We_rbf))) @ We_out
// F = (ResMLP(ssilu(m@Wf_in)) .* (rbf@Wf_rbf)) @ Wf_out
// All GEMMs via v_mfma_f32_16x16x32_bf16, f32 accumulation.
//
// R2 changes vs R1:
//  - force/energy: __launch_bounds__(256) only (no min-waves) -> allow ~160-190
//    VGPRs, kill the ~820 MB scratch spill traffic (WRITE_SIZE evidence).
//  - xbuf swizzle key (row&7)<<4 -> (row&12)<<3: epilogue u16 writes were
//    4-way bank-conflicted (q=0/2 and q=1/3 collided); new key spreads q into
//    byte bits 5-6 -> conflict-free writes, broadcast-friendly A reloads.

typedef __attribute__((ext_vector_type(8))) short bf16x8;
typedef __attribute__((ext_vector_type(4))) float f32x4;

#define INV_SQRT2 0.7071067811865476f

// ---- workspace layout (bytes) ----
#define XE_OFF     0ull
#define XE_BYTES   25600000ull                 // xE f32 [25000][256]
#define FWT_OFF    (XE_OFF + XE_BYTES)
#define FWT_BYTES  917504ull                   // 7 x [256][256] bf16, transposed+swizzled
#define EWT0_OFF   (FWT_OFF + FWT_BYTES)
#define EWT0_BYTES 65536ull                    // [128][256] bf16
#define EWTR_OFF   (EWT0_OFF + EWT0_BYTES)
#define EWTR_BYTES 196608ull                   // 6 x [128][128] bf16
#define W2F_OFF    (EWTR_OFF + EWTR_BYTES)
#define W2F_BYTES  16384ull                    // (Wf_rbf .* Wf_out)^T [256][32] bf16 (k padded)
#define W2E_OFF    (W2F_OFF + W2F_BYTES)
#define W2E_BYTES  16384ull                    // We_rbf^T [256][32] bf16 (k padded)

static __device__ __forceinline__ unsigned short f2bf(float f) {
  union { float f; unsigned u; } v; v.f = f;
  return (unsigned short)((v.u + 0x7fffu + ((v.u >> 16) & 1u)) >> 16);
}
static __device__ __forceinline__ float bf2f(unsigned short h) {
  union { unsigned u; float f; } v; v.u = ((unsigned)h) << 16;
  return v.f;
}
static __device__ __forceinline__ float ssilu(float x) {
  // silu(x)/0.6 = x * sigmoid(x) * 5/3
  return 1.6666666666666667f * x * __builtin_amdgcn_rcpf(1.0f + __expf(-x));
}
static __device__ __forceinline__ void gl16(const void* g, void* l) {
  // async global->LDS, 16B per lane; LDS dest is wave-uniform base + lane*16
  __builtin_amdgcn_global_load_lds(
      (const __attribute__((address_space(1))) void*)(unsigned long long)(uintptr_t)g,
      (__attribute__((address_space(3))) void*)(unsigned)(uintptr_t)l, 16, 0, 0);
}

// =====================================================================
// prep: weights f32 -> bf16, transposed to [out][in], XOR-swizzled so that
// LDS-linear staging via global_load_lds yields bank-conflict-free B reads.
// =====================================================================
__global__ void prep_kernel(const float* __restrict__ We_rbf,
                            const float* __restrict__ We_in,
                            const float* __restrict__ We_res,
                            const float* __restrict__ Wf_rbf,
                            const float* __restrict__ Wf_in,
                            const float* __restrict__ Wf_res,
                            const float* __restrict__ Wf_out,
                            char* __restrict__ ws) {
  int idx = blockIdx.x * 256 + threadIdx.x;
  if (idx < 458752) {  // FWt: 7 stages [k=256][c=256] -> [c][k]
    int s = idx >> 16, r = idx & 65535, k = r >> 8, c = r & 255;
    float v = (s == 0) ? Wf_in[k * 256 + c] : Wf_res[(s - 1) * 65536 + k * 256 + c];
    *(unsigned short*)(ws + FWT_OFF + (unsigned long long)s * 131072 +
                       c * 512 + ((k * 2) ^ ((c & 7) << 4))) = f2bf(v);
    return;
  }
  idx -= 458752;
  if (idx < 32768) {  // EWt0: [k=256][c=128] -> [c][k]
    int k = idx >> 7, c = idx & 127;
    *(unsigned short*)(ws + EWT0_OFF + c * 512 + ((k * 2) ^ ((c & 7) << 4))) = f2bf(We_in[k * 128 + c]);
    return;
  }
  idx -= 32768;
  if (idx < 98304) {  // EWtR: 6 stages [k=128][c=128] -> [c][k]
    int s = idx >> 14, r = idx & 16383, k = r >> 7, c = r & 127;
    *(unsigned short*)(ws + EWTR_OFF + (unsigned long long)s * 32768 +
                       c * 256 + ((k * 2) ^ ((c & 7) << 4))) = f2bf(We_res[s * 16384 + k * 128 + c]);
    return;
  }
  idx -= 98304;
  if (idx < 8192) {  // W2F: (Wf_rbf[k][c]*Wf_out[c])^T, k padded 16->32
    int c = idx >> 5, k = idx & 31;
    float v = (k < 16) ? Wf_rbf[k * 256 + c] * Wf_out[c] : 0.f;
    *(unsigned short*)(ws + W2F_OFF + c * 64 + ((k * 2) ^ ((c & 3) << 4))) = f2bf(v);
    return;
  }
  idx -= 8192;
  if (idx < 8192) {  // W2E: We_rbf^T, k padded
    int c = idx >> 5, k = idx & 31;
    float v = (k < 16) ? We_rbf[k * 256 + c] : 0.f;
    *(unsigned short*)(ws + W2E_OFF + c * 64 + ((k * 2) ^ ((c & 3) << 4))) = f2bf(v);
  }
}

// =====================================================================
// scatter: xE[id_j[e]] += m[e] .* (rbf[e] @ We_rbf)   (f32 atomics)
// 128 edges / block; rbf@We_rbf via MFMA (K=16 padded to 32).
// =====================================================================
__global__ __launch_bounds__(256) void scatter_kernel(
    const float* __restrict__ m, const float* __restrict__ rbf,
    const int* __restrict__ id_j, const char* __restrict__ W2E,
    float* __restrict__ xE, int nE) {
  __shared__ char rbfA[8192];   // [128][32] bf16, swizzled (row&3)<<4
  __shared__ char wb[16384];    // W2E staged
  __shared__ int sI[128];
  const int tid = threadIdx.x;
  const int lane = tid & 63, q = lane >> 4, r15 = lane & 15;
  const int wid = tid >> 6, wrow = wid * 32;
  const long long row0 = (long long)blockIdx.x * 128;
  const f32x4 zf = {0.f, 0.f, 0.f, 0.f};

#pragma unroll
  for (int i = 0; i < 8; ++i) {
    const int idx = tid * 8 + i;
    const int row = idx >> 4, d = idx & 15;
    long long rg = row0 + row; if (rg >= nE) rg = nE - 1;
    *(unsigned short*)(rbfA + row * 64 + ((d * 2) ^ ((row & 3) << 4))) = f2bf(rbf[rg * 16 + d]);
    *(unsigned short*)(rbfA + row * 64 + (((16 + d) * 2) ^ ((row & 3) << 4))) = 0;
  }
  if (tid < 128) {
    long long rg = row0 + tid;
    sI[tid] = (rg < nE) ? id_j[rg] : -1;
  }
#pragma unroll
  for (int i = 0; i < 4; ++i) gl16(W2E + i * 4096 + tid * 16, wb + i * 4096 + tid * 16);
  asm volatile("s_waitcnt vmcnt(0)" ::: "memory");
  __syncthreads();

  bf16x8 ar[2];
#pragma unroll
  for (int fr = 0; fr < 2; ++fr) {
    const int row = wrow + fr * 16 + r15;
    ar[fr] = *(const bf16x8*)(rbfA + row * 64 + ((q * 16) ^ ((row & 3) << 4)));
  }
#pragma unroll
  for (int fcg = 0; fcg < 16; ++fcg) {
    const int ci = fcg * 16 + r15;
    bf16x8 bw = *(const bf16x8*)(wb + ci * 64 + ((q * 16) ^ ((ci & 3) << 4)));
#pragma unroll
    for (int fr = 0; fr < 2; ++fr) {
      f32x4 rw = __builtin_amdgcn_mfma_f32_16x16x32_bf16(ar[fr], bw, zf, 0, 0, 0);
      const int col = fcg * 16 + r15;
#pragma unroll
      for (int j = 0; j < 4; ++j) {
        const int rowl = wrow + fr * 16 + q * 4 + j;
        const int aid = sI[rowl];
        if (aid >= 0) {
          const long long rg = row0 + rowl;
          float mv = m[rg * 256 + col];
          atomicAdd(&xE[(long long)aid * 256 + col], mv * rw[j]);
        }
      }
    }
  }
}

// =====================================================================
// force: fully fused 7-GEMM chain over [nE][256] + rbf gating + Wf_out dot
// 128 rows/block, 4 waves x 32 rows. A frags in regs; X round-trips a
// single 64KB swizzled LDS buffer; residual stream packed-bf16 in regs.
// =====================================================================
__global__ __launch_bounds__(256) void force_kernel(
    const float* __restrict__ m, const float* __restrict__ rbf,
    const char* __restrict__ FWt, const char* __restrict__ W2F,
    float* __restrict__ Fout, int nE) {
  __shared__ char xbuf[65536];  // [128][256] bf16, rows 512B, swz (row&12)<<3
  __shared__ char wbuf[16384];  // one 32-col weight chunk
  const int tid = threadIdx.x;
  const int lane = tid & 63, q = lane >> 4, r15 = lane & 15;
  const int wid = tid >> 6, wrow = wid * 32;
  const long long row0 = (long long)blockIdx.x * 128;
  const f32x4 zf = {0.f, 0.f, 0.f, 0.f};

  bf16x8 a[2][8];
  unsigned xs[8][2][2][2];  // residual stream x, packed 2xbf16, lane's D positions

  // stage-0 A frags from m (f32 -> bf16)
#pragma unroll
  for (int fr = 0; fr < 2; ++fr) {
#pragma unroll
    for (int ks = 0; ks < 8; ++ks) {
      long long rg = row0 + wrow + fr * 16 + r15; if (rg >= nE) rg = nE - 1;
      const float* p = m + rg * 256 + ks * 32 + q * 8;
      float4 v0 = *(const float4*)p;
      float4 v1 = *(const float4*)(p + 4);
      bf16x8 t;
      t[0] = (short)f2bf(v0.x); t[1] = (short)f2bf(v0.y);
      t[2] = (short)f2bf(v0.z); t[3] = (short)f2bf(v0.w);
      t[4] = (short)f2bf(v1.x); t[5] = (short)f2bf(v1.y);
      t[6] = (short)f2bf(v1.z); t[7] = (short)f2bf(v1.w);
      a[fr][ks] = t;
    }
  }

  for (int s = 0; s < 7; ++s) {
    const char* wsrc = FWt + (unsigned long long)s * 131072;
    const int isS0 = (s == 0);
    const int isRes = (s >= 2) && ((s & 1) == 0);
#pragma unroll
    for (int c = 0; c < 8; ++c) {
#pragma unroll
      for (int i = 0; i < 4; ++i)
        gl16(wsrc + c * 16384 + i * 4096 + tid * 16, wbuf + i * 4096 + tid * 16);
      asm volatile("s_waitcnt vmcnt(0)" ::: "memory");
      __syncthreads();

      f32x4 acc[2][2] = {{zf, zf}, {zf, zf}};
#pragma unroll
      for (int ks = 0; ks < 8; ++ks) {
        const int kb = (ks * 32 + q * 8) * 2;
        const int ci0 = r15, ci1 = 16 + r15;
        bf16x8 b0 = *(const bf16x8*)(wbuf + ci0 * 512 + (kb ^ ((ci0 & 7) << 4)));
        bf16x8 b1 = *(const bf16x8*)(wbuf + ci1 * 512 + (kb ^ ((ci1 & 7) << 4)));
        acc[0][0] = __builtin_amdgcn_mfma_f32_16x16x32_bf16(a[0][ks], b0, acc[0][0], 0, 0, 0);
        acc[1][0] = __builtin_amdgcn_mfma_f32_16x16x32_bf16(a[1][ks], b0, acc[1][0], 0, 0, 0);
        acc[0][1] = __builtin_amdgcn_mfma_f32_16x16x32_bf16(a[0][ks], b1, acc[0][1], 0, 0, 0);
        acc[1][1] = __builtin_amdgcn_mfma_f32_16x16x32_bf16(a[1][ks], b1, acc[1][1], 0, 0, 0);
      }
#pragma unroll
      for (int fr = 0; fr < 2; ++fr) {
#pragma unroll
        for (int fc = 0; fc < 2; ++fc) {
          float o0 = ssilu(acc[fr][fc][0]), o1 = ssilu(acc[fr][fc][1]);
          float o2 = ssilu(acc[fr][fc][2]), o3 = ssilu(acc[fr][fc][3]);
          if (isRes) {
            const unsigned p0 = xs[c][fr][fc][0], p1 = xs[c][fr][fc][1];
            o0 = (bf2f((unsigned short)(p0 & 0xffff)) + o0) * INV_SQRT2;
            o1 = (bf2f((unsigned short)(p0 >> 16)) + o1) * INV_SQRT2;
            o2 = (bf2f((unsigned short)(p1 & 0xffff)) + o2) * INV_SQRT2;
            o3 = (bf2f((unsigned short)(p1 >> 16)) + o3) * INV_SQRT2;
          }
          const unsigned short h0 = f2bf(o0), h1 = f2bf(o1), h2 = f2bf(o2), h3 = f2bf(o3);
          if (isS0 | isRes) {
            xs[c][fr][fc][0] = (unsigned)h0 | ((unsigned)h1 << 16);
            xs[c][fr][fc][1] = (unsigned)h2 | ((unsigned)h3 << 16);
          }
          if (s < 6) {
            const int colb = (c * 32 + fc * 16 + r15) * 2;
            const int rb = wrow + fr * 16 + q * 4;
            *(unsigned short*)(xbuf + (rb + 0) * 512 + (colb ^ (((rb + 0) & 12) << 3))) = h0;
            *(unsigned short*)(xbuf + (rb + 1) * 512 + (colb ^ (((rb + 1) & 12) << 3))) = h1;
            *(unsigned short*)(xbuf + (rb + 2) * 512 + (colb ^ (((rb + 2) & 12) << 3))) = h2;
            *(unsigned short*)(xbuf + (rb + 3) * 512 + (colb ^ (((rb + 3) & 12) << 3))) = h3;
          }
        }
      }
      __syncthreads();
    }
    if (s < 6) {  // reload A frags for next stage (chunk-0 barrier of next stage protects)
#pragma unroll
      for (int fr = 0; fr < 2; ++fr) {
#pragma unroll
        for (int ks = 0; ks < 8; ++ks) {
          const int row = wrow + fr * 16 + r15;
          const int kb = (ks * 32 + q * 8) * 2;
          a[fr][ks] = *(const bf16x8*)(xbuf + row * 512 + (kb ^ ((row & 12) << 3)));
        }
      }
    }
  }

  // ---- final: rbfw = rbf @ (Wf_rbf .* Wf_out);  F = sum_c x .* rbfw ----
#pragma unroll
  for (int i = 0; i < 8; ++i) {
    const int idx = tid * 8 + i;
    const int row = idx >> 4, d = idx & 15;
    long long rg = row0 + row; if (rg >= nE) rg = nE - 1;
    *(unsigned short*)(xbuf + row * 64 + ((d * 2) ^ ((row & 3) << 4))) = f2bf(rbf[rg * 16 + d]);
    *(unsigned short*)(xbuf + row * 64 + (((16 + d) * 2) ^ ((row & 3) << 4))) = 0;
  }
#pragma unroll
  for (int i = 0; i < 4; ++i) gl16(W2F + i * 4096 + tid * 16, wbuf + i * 4096 + tid * 16);
  asm volatile("s_waitcnt vmcnt(0)" ::: "memory");
  __syncthreads();

  bf16x8 ar[2];
#pragma unroll
  for (int fr = 0; fr < 2; ++fr) {
    const int row = wrow + fr * 16 + r15;
    ar[fr] = *(const bf16x8*)(xbuf + row * 64 + ((q * 16) ^ ((row & 3) << 4)));
  }
  float psum[2][4] = {{0.f, 0.f, 0.f, 0.f}, {0.f, 0.f, 0.f, 0.f}};
#pragma unroll
  for (int fcg = 0; fcg < 16; ++fcg) {
    const int ci = fcg * 16 + r15;
    bf16x8 bw = *(const bf16x8*)(wbuf + ci * 64 + ((q * 16) ^ ((ci & 3) << 4)));
#pragma unroll
    for (int fr = 0; fr < 2; ++fr) {
      f32x4 rw = __builtin_amdgcn_mfma_f32_16x16x32_bf16(ar[fr], bw, zf, 0, 0, 0);
      const unsigned p0 = xs[fcg >> 1][fr][fcg & 1][0];
      const unsigned p1 = xs[fcg >> 1][fr][fcg & 1][1];
      psum[fr][0] += bf2f((unsigned short)(p0 & 0xffff)) * rw[0];
      psum[fr][1] += bf2f((unsigned short)(p0 >> 16)) * rw[1];
      psum[fr][2] += bf2f((unsigned short)(p1 & 0xffff)) * rw[2];
      psum[fr][3] += bf2f((unsigned short)(p1 >> 16)) * rw[3];
    }
  }
#pragma unroll
  for (int off = 1; off < 16; off <<= 1) {
#pragma unroll
    for (int fr = 0; fr < 2; ++fr) {
#pragma unroll
      for (int j = 0; j < 4; ++j) psum[fr][j] += __shfl_xor(psum[fr][j], off, 64);
    }
  }
  if (r15 == 0) {
#pragma unroll
    for (int fr = 0; fr < 2; ++fr) {
#pragma unroll
      for (int j = 0; j < 4; ++j) {
        const long long rg = row0 + wrow + fr * 16 + q * 4 + j;
        if (rg < nE) Fout[rg] = psum[fr][j];
      }
    }
  }
}

// =====================================================================
// energy MLP: xE[25000][256] -> ssilu(@We_in[256x128]) -> 3 residual(128) -> @We_out
// =====================================================================
__global__ __launch_bounds__(256) void energy_kernel(
    const float* __restrict__ xE, const char* __restrict__ EWt0,
    const char* __restrict__ EWtR, const float* __restrict__ We_out,
    float* __restrict__ Eout, int nA) {
  __shared__ char xbuf[32768];  // [128][128] bf16, rows 256B
  __shared__ char wbuf[16384];
  const int tid = threadIdx.x;
  const int lane = tid & 63, q = lane >> 4, r15 = lane & 15;
  const int wid = tid >> 6, wrow = wid * 32;
  const long long row0 = (long long)blockIdx.x * 128;
  const f32x4 zf = {0.f, 0.f, 0.f, 0.f};

  bf16x8 a[2][8];
  unsigned xs[4][2][2][2];

#pragma unroll
  for (int fr = 0; fr < 2; ++fr) {
#pragma unroll
    for (int ks = 0; ks < 8; ++ks) {
      long long rg = row0 + wrow + fr * 16 + r15;
      bf16x8 t = {0, 0, 0, 0, 0, 0, 0, 0};
      if (rg < nA) {
        const float* p = xE + rg * 256 + ks * 32 + q * 8;
        float4 v0 = *(const float4*)p;
        float4 v1 = *(const float4*)(p + 4);
        t[0] = (short)f2bf(v0.x); t[1] = (short)f2bf(v0.y);
        t[2] = (short)f2bf(v0.z); t[3] = (short)f2bf(v0.w);
        t[4] = (short)f2bf(v1.x); t[5] = (short)f2bf(v1.y);
        t[6] = (short)f2bf(v1.z); t[7] = (short)f2bf(v1.w);
      }
      a[fr][ks] = t;
    }
  }

  for (int s = 0; s < 7; ++s) {
    const int K2 = (s == 0) ? 512 : 256;  // bytes per weight row
    const int wchunk = 32 * K2;
    const int nld = wchunk >> 12;         // 4 or 2 16B-loads per thread
    const char* wsrc = (s == 0) ? EWt0 : (EWtR + (unsigned long long)(s - 1) * 32768);
    const int isS0 = (s == 0);
    const int isRes = (s >= 2) && ((s & 1) == 0);
#pragma unroll
    for (int c = 0; c < 4; ++c) {
      for (int i = 0; i < nld; ++i)
        gl16(wsrc + c * wchunk + i * 4096 + tid * 16, wbuf + i * 4096 + tid * 16);
      asm volatile("s_waitcnt vmcnt(0)" ::: "memory");
      __syncthreads();

      f32x4 acc[2][2] = {{zf, zf}, {zf, zf}};
      if (s == 0) {
#pragma unroll
        for (int ks = 0; ks < 8; ++ks) {
          const int kb = (ks * 32 + q * 8) * 2;
          const int ci0 = r15, ci1 = 16 + r15;
          bf16x8 b0 = *(const bf16x8*)(wbuf + ci0 * 512 + (kb ^ ((ci0 & 7) << 4)));
          bf16x8 b1 = *(const bf16x8*)(wbuf + ci1 * 512 + (kb ^ ((ci1 & 7) << 4)));
          acc[0][0] = __builtin_amdgcn_mfma_f32_16x16x32_bf16(a[0][ks], b0, acc[0][0], 0, 0, 0);
          acc[1][0] = __builtin_amdgcn_mfma_f32_16x16x32_bf16(a[1][ks], b0, acc[1][0], 0, 0, 0);
          acc[0][1] = __builtin_amdgcn_mfma_f32_16x16x32_bf16(a[0][ks], b1, acc[0][1], 0, 0, 0);
          acc[1][1] = __builtin_amdgcn_mfma_f32_16x16x32_bf16(a[1][ks], b1, acc[1][1], 0, 0, 0);
        }
      } else {
#pragma unroll
        for (int ks = 0; ks < 4; ++ks) {
          const int kb = (ks * 32 + q * 8) * 2;
          const int ci0 = r15, ci1 = 16 + r15;
          bf16x8 b0 = *(const bf16x8*)(wbuf + ci0 * 256 + (kb ^ ((ci0 & 7) << 4)));
          bf16x8 b1 = *(const bf16x8*)(wbuf + ci1 * 256 + (kb ^ ((ci1 & 7) << 4)));
          acc[0][0] = __builtin_amdgcn_mfma_f32_16x16x32_bf16(a[0][ks], b0, acc[0][0], 0, 0, 0);
          acc[1][0] = __builtin_amdgcn_mfma_f32_16x16x32_bf16(a[1][ks], b0, acc[1][0], 0, 0, 0);
          acc[0][1] = __builtin_amdgcn_mfma_f32_16x16x32_bf16(a[0][ks], b1, acc[0][1], 0, 0, 0);
          acc[1][1] = __builtin_amdgcn_mfma_f32_16x16x32_bf16(a[1][ks], b1, acc[1][1], 0, 0, 0);
        }
      }
#pragma unroll
      for (int fr = 0; fr < 2; ++fr) {
#pragma unroll
        for (int fc = 0; fc < 2; ++fc) {
          float o0 = ssilu(acc[fr][fc][0]), o1 = ssilu(acc[fr][fc][1]);
          float o2 = ssilu(acc[fr][fc][2]), o3 = ssilu(acc[fr][fc][3]);
          if (isRes) {
            const unsigned p0 = xs[c][fr][fc][0], p1 = xs[c][fr][fc][1];
            o0 = (bf2f((unsigned short)(p0 & 0xffff)) + o0) * INV_SQRT2;
            o1 = (bf2f((unsigned short)(p0 >> 16)) + o1) * INV_SQRT2;
            o2 = (bf2f((unsigned short)(p1 & 0xffff)) + o2) * INV_SQRT2;
            o3 = (bf2f((unsigned short)(p1 >> 16)) + o3) * INV_SQRT2;
          }
          const unsigned short h0 = f2bf(o0), h1 = f2bf(o1), h2 = f2bf(o2), h3 = f2bf(o3);
          if (isS0 | isRes) {
            xs[c][fr][fc][0] = (unsigned)h0 | ((unsigned)h1 << 16);
            xs[c][fr][fc][1] = (unsigned)h2 | ((unsigned)h3 << 16);
          }
          if (s < 6) {
            const int colb = (c * 32 + fc * 16 + r15) * 2;
            const int rb = wrow + fr * 16 + q * 4;
            *(unsigned short*)(xbuf + (rb + 0) * 256 + (colb ^ (((rb + 0) & 12) << 3))) = h0;
            *(unsigned short*)(xbuf + (rb + 1) * 256 + (colb ^ (((rb + 1) & 12) << 3))) = h1;
            *(unsigned short*)(xbuf + (rb + 2) * 256 + (colb ^ (((rb + 2) & 12) << 3))) = h2;
            *(unsigned short*)(xbuf + (rb + 3) * 256 + (colb ^ (((rb + 3) & 12) << 3))) = h3;
          }
        }
      }
      __syncthreads();
    }
    if (s < 6) {
#pragma unroll
      for (int fr = 0; fr < 2; ++fr) {
#pragma unroll
        for (int ks = 0; ks < 4; ++ks) {
          const int row = wrow + fr * 16 + r15;
          const int kb = (ks * 32 + q * 8) * 2;
          a[fr][ks] = *(const bf16x8*)(xbuf + row * 256 + (kb ^ ((row & 12) << 3)));
        }
      }
    }
  }

  // final: E[row] = sum_c x[row,c] * We_out[c]
  float psum[2][4] = {{0.f, 0.f, 0.f, 0.f}, {0.f, 0.f, 0.f, 0.f}};
#pragma unroll
  for (int c = 0; c < 4; ++c) {
#pragma unroll
    for (int f = 0; f < 2; ++f) {
      const int col = c * 32 + f * 16 + r15;
      const float wo = We_out[col];
#pragma unroll
      for (int fr = 0; fr < 2; ++fr) {
        const unsigned p0 = xs[c][fr][f][0], p1 = xs[c][fr][f][1];
        psum[fr][0] += bf2f((unsigned short)(p0 & 0xffff)) * wo;
        psum[fr][1] += bf2f((unsigned short)(p0 >> 16)) * wo;
        psum[fr][2] += bf2f((unsigned short)(p1 & 0xffff)) * wo;
        psum[fr][3] += bf2f((unsigned short)(p1 >> 16)) * wo;
      }
    }
  }
#pragma unroll
  for (int off = 1; off < 16; off <<= 1) {
#pragma unroll
    for (int fr = 0; fr < 2; ++fr) {
#pragma unroll
      for (int j = 0; j < 4; ++j) psum[fr][j] += __shfl_xor(psum[fr][j], off, 64);
    }
  }
  if (r15 == 0) {
#pragma unroll
    for (int fr = 0; fr < 2; ++fr) {
#pragma unroll
      for (int j = 0; j < 4; ++j) {
        const long long rg = row0 + wrow + fr * 16 + q * 4 + j;
        if (rg < nA) Eout[rg] = psum[fr][j];
      }
    }
  }
}

// =====================================================================
extern "C" void kernel_launch(void* const* d_in, const int* in_sizes, int n_in,
                              void* d_out, int out_size, void* d_ws, size_t ws_size,
                              hipStream_t stream) {
  const float* m      = (const float*)d_in[1];
  const float* rbf    = (const float*)d_in[2];
  const int*   id_j   = (const int*)d_in[3];
  const float* We_rbf = (const float*)d_in[4];
  const float* We_in  = (const float*)d_in[5];
  const float* We_res = (const float*)d_in[6];
  const float* We_out = (const float*)d_in[7];
  const float* Wf_rbf = (const float*)d_in[8];
  const float* Wf_in  = (const float*)d_in[9];
  const float* Wf_res = (const float*)d_in[10];
  const float* Wf_out = (const float*)d_in[11];
  const int nA = in_sizes[0] / 128;   // 25000
  const int nE = in_sizes[1] / 256;   // 400000

  char* ws = (char*)d_ws;
  float* xE = (float*)(ws + XE_OFF);
  float* Eout = (float*)d_out;
  float* Fout = Eout + nA;

  prep_kernel<<<2368, 256, 0, stream>>>(We_rbf, We_in, We_res, Wf_rbf, Wf_in, Wf_res, Wf_out, ws);
  hipMemsetAsync(xE, 0, (size_t)nA * 256 * 4, stream);
  scatter_kernel<<<(nE + 127) / 128, 256, 0, stream>>>(m, rbf, id_j, ws + W2E_OFF, xE, nE);
  energy_kernel<<<(nA + 127) / 128, 256, 0, stream>>>(xE, ws + EWT0_OFF, ws + EWTR_OFF, We_out, Eout, nA);
  force_kernel<<<(nE + 127) / 128, 256, 0, stream>>>(m, rbf, ws + FWT_OFF, ws + W2F_OFF, Fout, nE);
}

// Round 3
// 1449.961 us; speedup vs baseline: 1.6340x; 1.0402x over previous
//
#include <hip/hip_runtime.h>
#include <stdint.h>

// GemNet OutputBlock fused kernels for MI355X (gfx950).
// E = MLP(segment_sum(m .* (rbf@We_rbf))) @ We_out
// F = (ResMLP(ssilu(m@Wf_in)) .* (rbf@Wf_rbf)) @ Wf_out
// All GEMMs via v_mfma_f32_16x16x32_bf16, f32 accumulation.
//
// R3 changes vs R2:
//  - All LDS swizzle keys -> (row&15)<<4 (4 row bits): per-16-lane-phase the
//    16 lanes now cover 16 distinct 16B slots -> conflict-free ds_read_b128.
//    (R1/R2 used 3 bits -> 8 slots -> 2-way conflict on every B read; the
//    6e7 SQ_LDS_BANK_CONFLICT was dominated by wbuf B reads.)
//  - force: 2-phase pipelined weight staging. Chunks of 16 cols (8KB),
//    wbuf[2][8192] double-buffer; issue next chunk's global_load_lds at top
//    of current chunk, one vmcnt(0)+barrier per chunk (drain hidden under
//    MFMA+epilogue). 112 chunks, 1 barrier each (was 2) + latency overlap.

typedef __attribute__((ext_vector_type(8))) short bf16x8;
typedef __attribute__((ext_vector_type(4))) float f32x4;

#define INV_SQRT2 0.7071067811865476f

// ---- workspace layout (bytes) ----
#define XE_OFF     0ull
#define XE_BYTES   25600000ull                 // xE f32 [25000][256]
#define FWT_OFF    (XE_OFF + XE_BYTES)
#define FWT_BYTES  917504ull                   // 7 x [256][256] bf16, transposed+swizzled
#define EWT0_OFF   (FWT_OFF + FWT_BYTES)
#define EWT0_BYTES 65536ull                    // [128][256] bf16
#define EWTR_OFF   (EWT0_OFF + EWT0_BYTES)
#define EWTR_BYTES 196608ull                   // 6 x [128][128] bf16
#define W2F_OFF    (EWTR_OFF + EWTR_BYTES)
#define W2F_BYTES  16384ull                    // (Wf_rbf .* Wf_out)^T [256][32] bf16 (k padded)
#define W2E_OFF    (W2F_OFF + W2F_BYTES)
#define W2E_BYTES  16384ull                    // We_rbf^T [256][32] bf16 (k padded)

static __device__ __forceinline__ unsigned short f2bf(float f) {
  union { float f; unsigned u; } v; v.f = f;
  return (unsigned short)((v.u + 0x7fffu + ((v.u >> 16) & 1u)) >> 16);
}
static __device__ __forceinline__ float bf2f(unsigned short h) {
  union { unsigned u; float f; } v; v.u = ((unsigned)h) << 16;
  return v.f;
}
static __device__ __forceinline__ float ssilu(float x) {
  // silu(x)/0.6 = x * sigmoid(x) * 5/3
  return 1.6666666666666667f * x * __builtin_amdgcn_rcpf(1.0f + __expf(-x));
}
static __device__ __forceinline__ void gl16(const void* g, void* l) {
  // async global->LDS, 16B per lane; LDS dest is wave-uniform base + lane*16
  __builtin_amdgcn_global_load_lds(
      (const __attribute__((address_space(1))) void*)(unsigned long long)(uintptr_t)g,
      (__attribute__((address_space(3))) void*)(unsigned)(uintptr_t)l, 16, 0, 0);
}

// =====================================================================
// prep: weights f32 -> bf16, transposed to [out][in], XOR-swizzled with
// 4-bit row key so LDS-linear staging yields conflict-free b128 reads.
// =====================================================================
__global__ void prep_kernel(const float* __restrict__ We_rbf,
                            const float* __restrict__ We_in,
                            const float* __restrict__ We_res,
                            const float* __restrict__ Wf_rbf,
                            const float* __restrict__ Wf_in,
                            const float* __restrict__ Wf_res,
                            const float* __restrict__ Wf_out,
                            char* __restrict__ ws) {
  int idx = blockIdx.x * 256 + threadIdx.x;
  if (idx < 458752) {  // FWt: 7 stages [k=256][c=256] -> [c][k]
    int s = idx >> 16, r = idx & 65535, k = r >> 8, c = r & 255;
    float v = (s == 0) ? Wf_in[k * 256 + c] : Wf_res[(s - 1) * 65536 + k * 256 + c];
    *(unsigned short*)(ws + FWT_OFF + (unsigned long long)s * 131072 +
                       c * 512 + ((k * 2) ^ ((c & 15) << 4))) = f2bf(v);
    return;
  }
  idx -= 458752;
  if (idx < 32768) {  // EWt0: [k=256][c=128] -> [c][k]
    int k = idx >> 7, c = idx & 127;
    *(unsigned short*)(ws + EWT0_OFF + c * 512 + ((k * 2) ^ ((c & 15) << 4))) = f2bf(We_in[k * 128 + c]);
    return;
  }
  idx -= 32768;
  if (idx < 98304) {  // EWtR: 6 stages [k=128][c=128] -> [c][k], rows 256B
    int s = idx >> 14, r = idx & 16383, k = r >> 7, c = r & 127;
    *(unsigned short*)(ws + EWTR_OFF + (unsigned long long)s * 32768 +
                       c * 256 + ((k * 2) ^ ((c & 15) << 4))) = f2bf(We_res[s * 16384 + k * 128 + c]);
    return;
  }
  idx -= 98304;
  if (idx < 8192) {  // W2F: (Wf_rbf[k][c]*Wf_out[c])^T, k padded 16->32
    int c = idx >> 5, k = idx & 31;
    float v = (k < 16) ? Wf_rbf[k * 256 + c] * Wf_out[c] : 0.f;
    *(unsigned short*)(ws + W2F_OFF + c * 64 + ((k * 2) ^ ((c & 3) << 4))) = f2bf(v);
    return;
  }
  idx -= 8192;
  if (idx < 8192) {  // W2E: We_rbf^T, k padded
    int c = idx >> 5, k = idx & 31;
    float v = (k < 16) ? We_rbf[k * 256 + c] : 0.f;
    *(unsigned short*)(ws + W2E_OFF + c * 64 + ((k * 2) ^ ((c & 3) << 4))) = f2bf(v);
  }
}

// =====================================================================
// scatter: xE[id_j[e]] += m[e] .* (rbf[e] @ We_rbf)   (f32 atomics)
// =====================================================================
__global__ __launch_bounds__(256) void scatter_kernel(
    const float* __restrict__ m, const float* __restrict__ rbf,
    const int* __restrict__ id_j, const char* __restrict__ W2E,
    float* __restrict__ xE, int nE) {
  __shared__ char rbfA[8192];   // [128][32] bf16, swizzled (row&3)<<4
  __shared__ char wb[16384];    // W2E staged
  __shared__ int sI[128];
  const int tid = threadIdx.x;
  const int lane = tid & 63, q = lane >> 4, r15 = lane & 15;
  const int wid = tid >> 6, wrow = wid * 32;
  const long long row0 = (long long)blockIdx.x * 128;
  const f32x4 zf = {0.f, 0.f, 0.f, 0.f};

#pragma unroll
  for (int i = 0; i < 8; ++i) {
    const int idx = tid * 8 + i;
    const int row = idx >> 4, d = idx & 15;
    long long rg = row0 + row; if (rg >= nE) rg = nE - 1;
    *(unsigned short*)(rbfA + row * 64 + ((d * 2) ^ ((row & 3) << 4))) = f2bf(rbf[rg * 16 + d]);
    *(unsigned short*)(rbfA + row * 64 + (((16 + d) * 2) ^ ((row & 3) << 4))) = 0;
  }
  if (tid < 128) {
    long long rg = row0 + tid;
    sI[tid] = (rg < nE) ? id_j[rg] : -1;
  }
#pragma unroll
  for (int i = 0; i < 4; ++i) gl16(W2E + i * 4096 + tid * 16, wb + i * 4096 + tid * 16);
  asm volatile("s_waitcnt vmcnt(0)" ::: "memory");
  __syncthreads();

  bf16x8 ar[2];
#pragma unroll
  for (int fr = 0; fr < 2; ++fr) {
    const int row = wrow + fr * 16 + r15;
    ar[fr] = *(const bf16x8*)(rbfA + row * 64 + ((q * 16) ^ ((row & 3) << 4)));
  }
#pragma unroll
  for (int fcg = 0; fcg < 16; ++fcg) {
    const int ci = fcg * 16 + r15;
    bf16x8 bw = *(const bf16x8*)(wb + ci * 64 + ((q * 16) ^ ((ci & 3) << 4)));
#pragma unroll
    for (int fr = 0; fr < 2; ++fr) {
      f32x4 rw = __builtin_amdgcn_mfma_f32_16x16x32_bf16(ar[fr], bw, zf, 0, 0, 0);
      const int col = fcg * 16 + r15;
#pragma unroll
      for (int j = 0; j < 4; ++j) {
        const int rowl = wrow + fr * 16 + q * 4 + j;
        const int aid = sI[rowl];
        if (aid >= 0) {
          const long long rg = row0 + rowl;
          float mv = m[rg * 256 + col];
          atomicAdd(&xE[(long long)aid * 256 + col], mv * rw[j]);
        }
      }
    }
  }
}

// =====================================================================
// force: fused 7-GEMM chain, 128 rows/block, 4 waves.
// 2-phase pipelined weight staging: 112 chunks x 8KB, wbuf double-buffered.
// =====================================================================
__global__ __launch_bounds__(256) void force_kernel(
    const float* __restrict__ m, const float* __restrict__ rbf,
    const char* __restrict__ FWt, const char* __restrict__ W2F,
    float* __restrict__ Fout, int nE) {
  __shared__ char xbuf[65536];    // [128][512B], swz key (row&15)<<4
  __shared__ char wbuf[2][8192];  // dbuf: 16 cols x 512B
  const int tid = threadIdx.x;
  const int lane = tid & 63, q = lane >> 4, r15 = lane & 15;
  const int wid = tid >> 6, wrow = wid * 32;
  const long long row0 = (long long)blockIdx.x * 128;
  const f32x4 zf = {0.f, 0.f, 0.f, 0.f};

  bf16x8 a[2][8];
  unsigned xs[16][2][2];  // residual stream, packed 2xbf16 per word

  // stage chunk 0 (its latency hides under the m prologue loads)
  gl16(FWt + tid * 16, wbuf[0] + tid * 16);
  gl16(FWt + 4096 + tid * 16, wbuf[0] + 4096 + tid * 16);

  // stage-0 A frags from m (f32 -> bf16)
#pragma unroll
  for (int fr = 0; fr < 2; ++fr) {
#pragma unroll
    for (int ks = 0; ks < 8; ++ks) {
      long long rg = row0 + wrow + fr * 16 + r15; if (rg >= nE) rg = nE - 1;
      const float* p = m + rg * 256 + ks * 32 + q * 8;
      float4 v0 = *(const float4*)p;
      float4 v1 = *(const float4*)(p + 4);
      bf16x8 t;
      t[0] = (short)f2bf(v0.x); t[1] = (short)f2bf(v0.y);
      t[2] = (short)f2bf(v0.z); t[3] = (short)f2bf(v0.w);
      t[4] = (short)f2bf(v1.x); t[5] = (short)f2bf(v1.y);
      t[6] = (short)f2bf(v1.z); t[7] = (short)f2bf(v1.w);
      a[fr][ks] = t;
    }
  }
  asm volatile("s_waitcnt vmcnt(0)" ::: "memory");
  __syncthreads();

  int curb = 0;
  for (int s = 0; s < 7; ++s) {
    const char* sbase = FWt + (unsigned long long)s * 131072;
    const int isS0 = (s == 0);
    const int isRes = (s >= 2) && ((s & 1) == 0);
#pragma unroll
    for (int c = 0; c < 16; ++c) {
      // issue next chunk's staging into the other buffer
      if (s < 6 || c < 15) {
        const char* src = sbase + (c + 1) * 8192;  // contiguous across stages
        gl16(src + tid * 16, wbuf[curb ^ 1] + tid * 16);
        gl16(src + 4096 + tid * 16, wbuf[curb ^ 1] + 4096 + tid * 16);
      }
      // compute current chunk (cols c*16..c*16+15)
      const char* wb = wbuf[curb];
      f32x4 acc[2] = {zf, zf};
#pragma unroll
      for (int ks = 0; ks < 8; ++ks) {
        const int kb = ks * 64 + q * 16;
        bf16x8 b = *(const bf16x8*)(wb + r15 * 512 + (kb ^ (r15 << 4)));
        acc[0] = __builtin_amdgcn_mfma_f32_16x16x32_bf16(a[0][ks], b, acc[0], 0, 0, 0);
        acc[1] = __builtin_amdgcn_mfma_f32_16x16x32_bf16(a[1][ks], b, acc[1], 0, 0, 0);
      }
#pragma unroll
      for (int fr = 0; fr < 2; ++fr) {
        float o0 = ssilu(acc[fr][0]), o1 = ssilu(acc[fr][1]);
        float o2 = ssilu(acc[fr][2]), o3 = ssilu(acc[fr][3]);
        if (isRes) {
          const unsigned p0 = xs[c][fr][0], p1 = xs[c][fr][1];
          o0 = (bf2f((unsigned short)(p0 & 0xffff)) + o0) * INV_SQRT2;
          o1 = (bf2f((unsigned short)(p0 >> 16)) + o1) * INV_SQRT2;
          o2 = (bf2f((unsigned short)(p1 & 0xffff)) + o2) * INV_SQRT2;
          o3 = (bf2f((unsigned short)(p1 >> 16)) + o3) * INV_SQRT2;
        }
        const unsigned short h0 = f2bf(o0), h1 = f2bf(o1), h2 = f2bf(o2), h3 = f2bf(o3);
        if (isS0 | isRes) {
          xs[c][fr][0] = (unsigned)h0 | ((unsigned)h1 << 16);
          xs[c][fr][1] = (unsigned)h2 | ((unsigned)h3 << 16);
        }
        if (s < 6) {
          const int colb = (c * 16 + r15) * 2;
          const int rb = wrow + fr * 16 + q * 4;
          *(unsigned short*)(xbuf + (rb + 0) * 512 + (colb ^ (((rb + 0) & 15) << 4))) = h0;
          *(unsigned short*)(xbuf + (rb + 1) * 512 + (colb ^ (((rb + 1) & 15) << 4))) = h1;
          *(unsigned short*)(xbuf + (rb + 2) * 512 + (colb ^ (((rb + 2) & 15) << 4))) = h2;
          *(unsigned short*)(xbuf + (rb + 3) * 512 + (colb ^ (((rb + 3) & 15) << 4))) = h3;
        }
      }
      asm volatile("s_waitcnt vmcnt(0)" ::: "memory");  // next chunk landed
      __syncthreads();  // wbuf[curb] reads + xbuf writes complete block-wide
      curb ^= 1;
    }
    if (s < 6) {  // A frags for next stage
#pragma unroll
      for (int fr = 0; fr < 2; ++fr) {
#pragma unroll
        for (int ks = 0; ks < 8; ++ks) {
          const int row = wrow + fr * 16 + r15;
          const int kb = ks * 64 + q * 16;
          a[fr][ks] = *(const bf16x8*)(xbuf + row * 512 + (kb ^ (r15 << 4)));
        }
      }
      __syncthreads();  // protect xbuf from next stage's epilogue writes
    }
  }

  // ---- final: rbfw = rbf @ (Wf_rbf .* Wf_out);  F = sum_c x .* rbfw ----
#pragma unroll
  for (int i = 0; i < 4; ++i) gl16(W2F + i * 4096 + tid * 16, wbuf[0] + i * 4096 + tid * 16);
#pragma unroll
  for (int i = 0; i < 8; ++i) {
    const int idx = tid * 8 + i;
    const int row = idx >> 4, d = idx & 15;
    long long rg = row0 + row; if (rg >= nE) rg = nE - 1;
    *(unsigned short*)(xbuf + row * 64 + ((d * 2) ^ ((row & 3) << 4))) = f2bf(rbf[rg * 16 + d]);
    *(unsigned short*)(xbuf + row * 64 + (((16 + d) * 2) ^ ((row & 3) << 4))) = 0;
  }
  asm volatile("s_waitcnt vmcnt(0)" ::: "memory");
  __syncthreads();

  bf16x8 ar[2];
#pragma unroll
  for (int fr = 0; fr < 2; ++fr) {
    const int row = wrow + fr * 16 + r15;
    ar[fr] = *(const bf16x8*)(xbuf + row * 64 + ((q * 16) ^ ((row & 3) << 4)));
  }
  float psum[2][4] = {{0.f, 0.f, 0.f, 0.f}, {0.f, 0.f, 0.f, 0.f}};
#pragma unroll
  for (int fcg = 0; fcg < 16; ++fcg) {
    const int ci = fcg * 16 + r15;
    bf16x8 bw = *(const bf16x8*)(wbuf[0] + ci * 64 + ((q * 16) ^ ((ci & 3) << 4)));
#pragma unroll
    for (int fr = 0; fr < 2; ++fr) {
      f32x4 rw = __builtin_amdgcn_mfma_f32_16x16x32_bf16(ar[fr], bw, zf, 0, 0, 0);
      const unsigned p0 = xs[fcg][fr][0];
      const unsigned p1 = xs[fcg][fr][1];
      psum[fr][0] += bf2f((unsigned short)(p0 & 0xffff)) * rw[0];
      psum[fr][1] += bf2f((unsigned short)(p0 >> 16)) * rw[1];
      psum[fr][2] += bf2f((unsigned short)(p1 & 0xffff)) * rw[2];
      psum[fr][3] += bf2f((unsigned short)(p1 >> 16)) * rw[3];
    }
  }
#pragma unroll
  for (int off = 1; off < 16; off <<= 1) {
#pragma unroll
    for (int fr = 0; fr < 2; ++fr) {
#pragma unroll
      for (int j = 0; j < 4; ++j) psum[fr][j] += __shfl_xor(psum[fr][j], off, 64);
    }
  }
  if (r15 == 0) {
#pragma unroll
    for (int fr = 0; fr < 2; ++fr) {
#pragma unroll
      for (int j = 0; j < 4; ++j) {
        const long long rg = row0 + wrow + fr * 16 + q * 4 + j;
        if (rg < nE) Fout[rg] = psum[fr][j];
      }
    }
  }
}

// =====================================================================
// energy MLP: xE[25000][256] -> ssilu(@We_in[256x128]) -> 3 residual(128) -> @We_out
// (small: 196 blocks; keys updated to 4-bit swizzle, structure unchanged)
// =====================================================================
__global__ __launch_bounds__(256) void energy_kernel(
    const float* __restrict__ xE, const char* __restrict__ EWt0,
    const char* __restrict__ EWtR, const float* __restrict__ We_out,
    float* __restrict__ Eout, int nA) {
  __shared__ char xbuf[32768];  // [128][256B], swz key (row&15)<<4
  __shared__ char wbuf[16384];
  const int tid = threadIdx.x;
  const int lane = tid & 63, q = lane >> 4, r15 = lane & 15;
  const int wid = tid >> 6, wrow = wid * 32;
  const long long row0 = (long long)blockIdx.x * 128;
  const f32x4 zf = {0.f, 0.f, 0.f, 0.f};

  bf16x8 a[2][8];
  unsigned xs[4][2][2][2];

#pragma unroll
  for (int fr = 0; fr < 2; ++fr) {
#pragma unroll
    for (int ks = 0; ks < 8; ++ks) {
      long long rg = row0 + wrow + fr * 16 + r15;
      bf16x8 t = {0, 0, 0, 0, 0, 0, 0, 0};
      if (rg < nA) {
        const float* p = xE + rg * 256 + ks * 32 + q * 8;
        float4 v0 = *(const float4*)p;
        float4 v1 = *(const float4*)(p + 4);
        t[0] = (short)f2bf(v0.x); t[1] = (short)f2bf(v0.y);
        t[2] = (short)f2bf(v0.z); t[3] = (short)f2bf(v0.w);
        t[4] = (short)f2bf(v1.x); t[5] = (short)f2bf(v1.y);
        t[6] = (short)f2bf(v1.z); t[7] = (short)f2bf(v1.w);
      }
      a[fr][ks] = t;
    }
  }

  for (int s = 0; s < 7; ++s) {
    const int K2 = (s == 0) ? 512 : 256;  // bytes per weight row
    const int wchunk = 32 * K2;
    const int nld = wchunk >> 12;         // 4 or 2 16B-loads per thread
    const char* wsrc = (s == 0) ? EWt0 : (EWtR + (unsigned long long)(s - 1) * 32768);
    const int isS0 = (s == 0);
    const int isRes = (s >= 2) && ((s & 1) == 0);
#pragma unroll
    for (int c = 0; c < 4; ++c) {
      for (int i = 0; i < nld; ++i)
        gl16(wsrc + c * wchunk + i * 4096 + tid * 16, wbuf + i * 4096 + tid * 16);
      asm volatile("s_waitcnt vmcnt(0)" ::: "memory");
      __syncthreads();

      f32x4 acc[2][2] = {{zf, zf}, {zf, zf}};
      if (s == 0) {
#pragma unroll
        for (int ks = 0; ks < 8; ++ks) {
          const int kb = ks * 64 + q * 16;
          const int ci0 = r15, ci1 = 16 + r15;
          bf16x8 b0 = *(const bf16x8*)(wbuf + ci0 * 512 + (kb ^ ((ci0 & 15) << 4)));
          bf16x8 b1 = *(const bf16x8*)(wbuf + ci1 * 512 + (kb ^ ((ci1 & 15) << 4)));
          acc[0][0] = __builtin_amdgcn_mfma_f32_16x16x32_bf16(a[0][ks], b0, acc[0][0], 0, 0, 0);
          acc[1][0] = __builtin_amdgcn_mfma_f32_16x16x32_bf16(a[1][ks], b0, acc[1][0], 0, 0, 0);
          acc[0][1] = __builtin_amdgcn_mfma_f32_16x16x32_bf16(a[0][ks], b1, acc[0][1], 0, 0, 0);
          acc[1][1] = __builtin_amdgcn_mfma_f32_16x16x32_bf16(a[1][ks], b1, acc[1][1], 0, 0, 0);
        }
      } else {
#pragma unroll
        for (int ks = 0; ks < 4; ++ks) {
          const int kb = ks * 64 + q * 16;
          const int ci0 = r15, ci1 = 16 + r15;
          bf16x8 b0 = *(const bf16x8*)(wbuf + ci0 * 256 + (kb ^ ((ci0 & 15) << 4)));
          bf16x8 b1 = *(const bf16x8*)(wbuf + ci1 * 256 + (kb ^ ((ci1 & 15) << 4)));
          acc[0][0] = __builtin_amdgcn_mfma_f32_16x16x32_bf16(a[0][ks], b0, acc[0][0], 0, 0, 0);
          acc[1][0] = __builtin_amdgcn_mfma_f32_16x16x32_bf16(a[1][ks], b0, acc[1][0], 0, 0, 0);
          acc[0][1] = __builtin_amdgcn_mfma_f32_16x16x32_bf16(a[0][ks], b1, acc[0][1], 0, 0, 0);
          acc[1][1] = __builtin_amdgcn_mfma_f32_16x16x32_bf16(a[1][ks], b1, acc[1][1], 0, 0, 0);
        }
      }
#pragma unroll
      for (int fr = 0; fr < 2; ++fr) {
#pragma unroll
        for (int fc = 0; fc < 2; ++fc) {
          float o0 = ssilu(acc[fr][fc][0]), o1 = ssilu(acc[fr][fc][1]);
          float o2 = ssilu(acc[fr][fc][2]), o3 = ssilu(acc[fr][fc][3]);
          if (isRes) {
            const unsigned p0 = xs[c][fr][fc][0], p1 = xs[c][fr][fc][1];
            o0 = (bf2f((unsigned short)(p0 & 0xffff)) + o0) * INV_SQRT2;
            o1 = (bf2f((unsigned short)(p0 >> 16)) + o1) * INV_SQRT2;
            o2 = (bf2f((unsigned short)(p1 & 0xffff)) + o2) * INV_SQRT2;
            o3 = (bf2f((unsigned short)(p1 >> 16)) + o3) * INV_SQRT2;
          }
          const unsigned short h0 = f2bf(o0), h1 = f2bf(o1), h2 = f2bf(o2), h3 = f2bf(o3);
          if (isS0 | isRes) {
            xs[c][fr][fc][0] = (unsigned)h0 | ((unsigned)h1 << 16);
            xs[c][fr][fc][1] = (unsigned)h2 | ((unsigned)h3 << 16);
          }
          if (s < 6) {
            const int colb = (c * 32 + fc * 16 + r15) * 2;
            const int rb = wrow + fr * 16 + q * 4;
            *(unsigned short*)(xbuf + (rb + 0) * 256 + (colb ^ (((rb + 0) & 15) << 4))) = h0;
            *(unsigned short*)(xbuf + (rb + 1) * 256 + (colb ^ (((rb + 1) & 15) << 4))) = h1;
            *(unsigned short*)(xbuf + (rb + 2) * 256 + (colb ^ (((rb + 2) & 15) << 4))) = h2;
            *(unsigned short*)(xbuf + (rb + 3) * 256 + (colb ^ (((rb + 3) & 15) << 4))) = h3;
          }
        }
      }
      __syncthreads();
    }
    if (s < 6) {
#pragma unroll
      for (int fr = 0; fr < 2; ++fr) {
#pragma unroll
        for (int ks = 0; ks < 4; ++ks) {
          const int row = wrow + fr * 16 + r15;
          const int kb = ks * 64 + q * 16;
          a[fr][ks] = *(const bf16x8*)(xbuf + row * 256 + (kb ^ (r15 << 4)));
        }
      }
      __syncthreads();
    }
  }

  // final: E[row] = sum_c x[row,c] * We_out[c]
  float psum[2][4] = {{0.f, 0.f, 0.f, 0.f}, {0.f, 0.f, 0.f, 0.f}};
#pragma unroll
  for (int c = 0; c < 4; ++c) {
#pragma unroll
    for (int f = 0; f < 2; ++f) {
      const int col = c * 32 + f * 16 + r15;
      const float wo = We_out[col];
#pragma unroll
      for (int fr = 0; fr < 2; ++fr) {
        const unsigned p0 = xs[c][fr][f][0], p1 = xs[c][fr][f][1];
        psum[fr][0] += bf2f((unsigned short)(p0 & 0xffff)) * wo;
        psum[fr][1] += bf2f((unsigned short)(p0 >> 16)) * wo;
        psum[fr][2] += bf2f((unsigned short)(p1 & 0xffff)) * wo;
        psum[fr][3] += bf2f((unsigned short)(p1 >> 16)) * wo;
      }
    }
  }
#pragma unroll
  for (int off = 1; off < 16; off <<= 1) {
#pragma unroll
    for (int fr = 0; fr < 2; ++fr) {
#pragma unroll
      for (int j = 0; j < 4; ++j) psum[fr][j] += __shfl_xor(psum[fr][j], off, 64);
    }
  }
  if (r15 == 0) {
#pragma unroll
    for (int fr = 0; fr < 2; ++fr) {
#pragma unroll
      for (int j = 0; j < 4; ++j) {
        const long long rg = row0 + wrow + fr * 16 + q * 4 + j;
        if (rg < nA) Eout[rg] = psum[fr][j];
      }
    }
  }
}

// =====================================================================
extern "C" void kernel_launch(void* const* d_in, const int* in_sizes, int n_in,
                              void* d_out, int out_size, void* d_ws, size_t ws_size,
                              hipStream_t stream) {
  const float* m      = (const float*)d_in[1];
  const float* rbf    = (const float*)d_in[2];
  const int*   id_j   = (const int*)d_in[3];
  const float* We_rbf = (const float*)d_in[4];
  const float* We_in  = (const float*)d_in[5];
  const float* We_res = (const float*)d_in[6];
  const float* We_out = (const float*)d_in[7];
  const float* Wf_rbf = (const float*)d_in[8];
  const float* Wf_in  = (const float*)d_in[9];
  const float* Wf_res = (const float*)d_in[10];
  const float* Wf_out = (const float*)d_in[11];
  const int nA = in_sizes[0] / 128;   // 25000
  const int nE = in_sizes[1] / 256;   // 400000

  char* ws = (char*)d_ws;
  float* xE = (float*)(ws + XE_OFF);
  float* Eout = (float*)d_out;
  float* Fout = Eout + nA;

  prep_kernel<<<2368, 256, 0, stream>>>(We_rbf, We_in, We_res, Wf_rbf, Wf_in, Wf_res, Wf_out, ws);
  hipMemsetAsync(xE, 0, (size_t)nA * 256 * 4, stream);
  scatter_kernel<<<(nE + 127) / 128, 256, 0, stream>>>(m, rbf, id_j, ws + W2E_OFF, xE, nE);
  energy_kernel<<<(nA + 127) / 128, 256, 0, stream>>>(xE, ws + EWT0_OFF, ws + EWTR_OFF, We_out, Eout, nA);
  force_kernel<<<(nE + 127) / 128, 256, 0, stream>>>(m, rbf, ws + FWT_OFF, ws + W2F_OFF, Fout, nE);
}

// Round 4
// 1156.528 us; speedup vs baseline: 2.0486x; 1.2537x over previous
//
#include <hip/hip_runtime.h>
#include <stdint.h>

// GemNet OutputBlock fused kernels for MI355X (gfx950).
// E = MLP(segment_sum(m .* (rbf@We_rbf))) @ We_out
// F = (ResMLP(ssilu(m@Wf_in)) .* (rbf@Wf_rbf)) @ Wf_out
//
// R4 changes vs R3 (force_kernel rewritten):
//  - Swapped-operand MFMA chain: acc = mfma(Wfrag, Xfrag) computes Y^T, so
//    each lane's stage outputs belong to its OWN rows -> next-stage B-frags
//    rebuilt via a fixed 4-lane shfl permutation. No x LDS round-trip at all.
//  - LDS = 4 x 16KB weight double..quad buffer; depth-3 counted-vmcnt(8)
//    pipeline with raw s_barrier (1 barrier/chunk, 57 total vs ~230).
//  - 32-col chunks: chunk t fills exactly b_next[rt][t] (k-slot t).
//  - Residual checkpoint xs + input bA + building bB = ~240 VGPR;
//    __launch_bounds__(256,2) caps 256 (2 waves/SIMD).

typedef __attribute__((ext_vector_type(8))) short bf16x8;
typedef __attribute__((ext_vector_type(4))) float f32x4;
typedef __attribute__((ext_vector_type(4))) unsigned u32x4;

#define INV_SQRT2 0.7071067811865476f

// ---- workspace layout (bytes) ----
#define XE_OFF     0ull
#define XE_BYTES   25600000ull                 // xE f32 [25000][256]
#define FWT_OFF    (XE_OFF + XE_BYTES)
#define FWT_BYTES  917504ull                   // 7 x [256][256] bf16, transposed+swizzled
#define EWT0_OFF   (FWT_OFF + FWT_BYTES)
#define EWT0_BYTES 65536ull                    // [128][256] bf16
#define EWTR_OFF   (EWT0_OFF + EWT0_BYTES)
#define EWTR_BYTES 196608ull                   // 6 x [128][128] bf16
#define W2F_OFF    (EWTR_OFF + EWTR_BYTES)
#define W2F_BYTES  16384ull                    // (Wf_rbf .* Wf_out)^T [256][32] bf16 (k padded)
#define W2E_OFF    (W2F_OFF + W2F_BYTES)
#define W2E_BYTES  16384ull                    // We_rbf^T [256][32] bf16 (k padded)

static __device__ __forceinline__ unsigned short f2bf(float f) {
  union { float f; unsigned u; } v; v.f = f;
  return (unsigned short)((v.u + 0x7fffu + ((v.u >> 16) & 1u)) >> 16);
}
static __device__ __forceinline__ float bf2f(unsigned short h) {
  union { unsigned u; float f; } v; v.u = ((unsigned)h) << 16;
  return v.f;
}
static __device__ __forceinline__ float ssilu(float x) {
  // silu(x)/0.6 = x * sigmoid(x) * 5/3
  return 1.6666666666666667f * x * __builtin_amdgcn_rcpf(1.0f + __expf(-x));
}
static __device__ __forceinline__ void gl16(const void* g, void* l) {
  // async global->LDS, 16B per lane; LDS dest is wave-uniform base + lane*16
  __builtin_amdgcn_global_load_lds(
      (const __attribute__((address_space(1))) void*)(unsigned long long)(uintptr_t)g,
      (__attribute__((address_space(3))) void*)(unsigned)(uintptr_t)l, 16, 0, 0);
}

// =====================================================================
// prep: weights f32 -> bf16, transposed to [out][in], XOR-swizzled with
// 4-bit row key so LDS-linear staging yields conflict-free b128 reads.
// =====================================================================
__global__ void prep_kernel(const float* __restrict__ We_rbf,
                            const float* __restrict__ We_in,
                            const float* __restrict__ We_res,
                            const float* __restrict__ Wf_rbf,
                            const float* __restrict__ Wf_in,
                            const float* __restrict__ Wf_res,
                            const float* __restrict__ Wf_out,
                            char* __restrict__ ws) {
  int idx = blockIdx.x * 256 + threadIdx.x;
  if (idx < 458752) {  // FWt: 7 stages [k=256][c=256] -> [c][k]
    int s = idx >> 16, r = idx & 65535, k = r >> 8, c = r & 255;
    float v = (s == 0) ? Wf_in[k * 256 + c] : Wf_res[(s - 1) * 65536 + k * 256 + c];
    *(unsigned short*)(ws + FWT_OFF + (unsigned long long)s * 131072 +
                       c * 512 + ((k * 2) ^ ((c & 15) << 4))) = f2bf(v);
    return;
  }
  idx -= 458752;
  if (idx < 32768) {  // EWt0: [k=256][c=128] -> [c][k]
    int k = idx >> 7, c = idx & 127;
    *(unsigned short*)(ws + EWT0_OFF + c * 512 + ((k * 2) ^ ((c & 15) << 4))) = f2bf(We_in[k * 128 + c]);
    return;
  }
  idx -= 32768;
  if (idx < 98304) {  // EWtR: 6 stages [k=128][c=128] -> [c][k], rows 256B
    int s = idx >> 14, r = idx & 16383, k = r >> 7, c = r & 127;
    *(unsigned short*)(ws + EWTR_OFF + (unsigned long long)s * 32768 +
                       c * 256 + ((k * 2) ^ ((c & 15) << 4))) = f2bf(We_res[s * 16384 + k * 128 + c]);
    return;
  }
  idx -= 98304;
  if (idx < 8192) {  // W2F: (Wf_rbf[k][c]*Wf_out[c])^T, k padded 16->32
    int c = idx >> 5, k = idx & 31;
    float v = (k < 16) ? Wf_rbf[k * 256 + c] * Wf_out[c] : 0.f;
    *(unsigned short*)(ws + W2F_OFF + c * 64 + ((k * 2) ^ ((c & 3) << 4))) = f2bf(v);
    return;
  }
  idx -= 8192;
  if (idx < 8192) {  // W2E: We_rbf^T, k padded
    int c = idx >> 5, k = idx & 31;
    float v = (k < 16) ? We_rbf[k * 256 + c] : 0.f;
    *(unsigned short*)(ws + W2E_OFF + c * 64 + ((k * 2) ^ ((c & 3) << 4))) = f2bf(v);
  }
}

// =====================================================================
// scatter: xE[id_j[e]] += m[e] .* (rbf[e] @ We_rbf)   (f32 atomics)
// =====================================================================
__global__ __launch_bounds__(256) void scatter_kernel(
    const float* __restrict__ m, const float* __restrict__ rbf,
    const int* __restrict__ id_j, const char* __restrict__ W2E,
    float* __restrict__ xE, int nE) {
  __shared__ char rbfA[8192];   // [128][32] bf16, swizzled (row&3)<<4
  __shared__ char wb[16384];    // W2E staged
  __shared__ int sI[128];
  const int tid = threadIdx.x;
  const int lane = tid & 63, q = lane >> 4, r15 = lane & 15;
  const int wid = tid >> 6, wrow = wid * 32;
  const long long row0 = (long long)blockIdx.x * 128;
  const f32x4 zf = {0.f, 0.f, 0.f, 0.f};

#pragma unroll
  for (int i = 0; i < 8; ++i) {
    const int idx = tid * 8 + i;
    const int row = idx >> 4, d = idx & 15;
    long long rg = row0 + row; if (rg >= nE) rg = nE - 1;
    *(unsigned short*)(rbfA + row * 64 + ((d * 2) ^ ((row & 3) << 4))) = f2bf(rbf[rg * 16 + d]);
    *(unsigned short*)(rbfA + row * 64 + (((16 + d) * 2) ^ ((row & 3) << 4))) = 0;
  }
  if (tid < 128) {
    long long rg = row0 + tid;
    sI[tid] = (rg < nE) ? id_j[rg] : -1;
  }
#pragma unroll
  for (int i = 0; i < 4; ++i) gl16(W2E + i * 4096 + tid * 16, wb + i * 4096 + tid * 16);
  asm volatile("s_waitcnt vmcnt(0)" ::: "memory");
  __syncthreads();

  bf16x8 ar[2];
#pragma unroll
  for (int fr = 0; fr < 2; ++fr) {
    const int row = wrow + fr * 16 + r15;
    ar[fr] = *(const bf16x8*)(rbfA + row * 64 + ((q * 16) ^ ((row & 3) << 4)));
  }
#pragma unroll
  for (int fcg = 0; fcg < 16; ++fcg) {
    const int ci = fcg * 16 + r15;
    bf16x8 bw = *(const bf16x8*)(wb + ci * 64 + ((q * 16) ^ ((ci & 3) << 4)));
#pragma unroll
    for (int fr = 0; fr < 2; ++fr) {
      f32x4 rw = __builtin_amdgcn_mfma_f32_16x16x32_bf16(ar[fr], bw, zf, 0, 0, 0);
      const int col = fcg * 16 + r15;
#pragma unroll
      for (int j = 0; j < 4; ++j) {
        const int rowl = wrow + fr * 16 + q * 4 + j;
        const int aid = sI[rowl];
        if (aid >= 0) {
          const long long rg = row0 + rowl;
          float mv = m[rg * 256 + col];
          atomicAdd(&xE[(long long)aid * 256 + col], mv * rw[j]);
        }
      }
    }
  }
}

// =====================================================================
// force: swapped-operand fused 7-GEMM chain, 128 rows/block, 4 waves x 32.
// No xbuf; depth-3 counted-vmcnt weight pipeline; 1 raw barrier per chunk.
// Chunk = 32 cols (16KB). 57 chunks total (56 chain + 1 W2F).
// =====================================================================
__global__ __launch_bounds__(256, 2) void force_kernel(
    const float* __restrict__ m, const float* __restrict__ rbf,
    const char* __restrict__ FWt, const char* __restrict__ W2F,
    float* __restrict__ Fout, int nE) {
  __shared__ char wbuf[4][16384];
  const int tid = threadIdx.x;
  const int lane = tid & 63, q = lane >> 4, r15 = lane & 15;
  const int wid = tid >> 6, wrow = wid * 32;
  const long long row0 = (long long)blockIdx.x * 128;
  const f32x4 zf = {0.f, 0.f, 0.f, 0.f};
  const bool qh = (q >> 1) != 0;
  const int sA = ((q & 1) << 5) | r15;  // src lane for b-words 0,1
  const int sB = sA + 16;               // src lane for b-words 2,3

  long long rg[2];
  rg[0] = row0 + wrow + r15; if (rg[0] >= nE) rg[0] = nE - 1;
  rg[1] = row0 + wrow + 16 + r15; if (rg[1] >= nE) rg[1] = nE - 1;

  // stage chunks 0..2 (oldest VMEM ops -> counted vmcnt works)
#pragma unroll
  for (int cc = 0; cc < 3; ++cc)
#pragma unroll
    for (int i = 0; i < 4; ++i)
      gl16(FWt + cc * 16384 + i * 4096 + tid * 16, wbuf[cc] + i * 4096 + tid * 16);

  bf16x8 bA[2][8], bB[2][8];
  unsigned xs[8][2][2][2];  // residual checkpoint, c-layout [t][rt][f][p]

  // B-frags (= rows of m) : bA[rt][ks][e] = m[row][ks*32+q*8+e]
#pragma unroll
  for (int rt = 0; rt < 2; ++rt)
#pragma unroll
    for (int ks = 0; ks < 8; ++ks) {
      const float* p = m + rg[rt] * 256 + ks * 32 + q * 8;
      float4 v0 = *(const float4*)p;
      float4 v1 = *(const float4*)(p + 4);
      bf16x8 t;
      t[0] = (short)f2bf(v0.x); t[1] = (short)f2bf(v0.y);
      t[2] = (short)f2bf(v0.z); t[3] = (short)f2bf(v0.w);
      t[4] = (short)f2bf(v1.x); t[5] = (short)f2bf(v1.y);
      t[6] = (short)f2bf(v1.z); t[7] = (short)f2bf(v1.w);
      bA[rt][ks] = t;
    }

  for (int s = 0; s < 7; ++s) {
    const bool isS0 = (s == 0);
    const bool isRes = (s >= 2) && !(s & 1);
#pragma unroll
    for (int t = 0; t < 8; ++t) {
      const int c = s * 8 + t;
      // chunk c's loads done (c+1,c+2 still in flight = 8 outstanding)
      asm volatile("s_waitcnt vmcnt(8)" ::: "memory");
      __builtin_amdgcn_s_barrier();
      {  // issue chunk c+3 (clamped re-stage of W2F at the tail keeps
         // outstanding count uniform so vmcnt(8) is always correct)
        int cs = c + 3; if (cs > 56) cs = 56;
        const char* src = (cs < 56) ? (FWt + (unsigned long long)cs * 16384) : W2F;
        char* dst = (char*)wbuf + ((t + 3) & 3) * 16384;  // (c+3)&3 == (t+3)&3
#pragma unroll
        for (int i = 0; i < 4; ++i)
          gl16(src + i * 4096 + tid * 16, dst + i * 4096 + tid * 16);
      }
      const char* wb = (const char*)wbuf + (t & 3) * 16384;
      f32x4 acc[2][2] = {{zf, zf}, {zf, zf}};
#pragma unroll
      for (int ks = 0; ks < 8; ++ks) {
        const int kb = ks * 64 + q * 16;
        bf16x8 w0 = *(const bf16x8*)(wb + r15 * 512 + (kb ^ (r15 << 4)));
        bf16x8 w1 = *(const bf16x8*)(wb + (16 + r15) * 512 + (kb ^ (r15 << 4)));
        acc[0][0] = __builtin_amdgcn_mfma_f32_16x16x32_bf16(w0, bA[0][ks], acc[0][0], 0, 0, 0);
        acc[1][0] = __builtin_amdgcn_mfma_f32_16x16x32_bf16(w0, bA[1][ks], acc[1][0], 0, 0, 0);
        acc[0][1] = __builtin_amdgcn_mfma_f32_16x16x32_bf16(w1, bA[0][ks], acc[0][1], 0, 0, 0);
        acc[1][1] = __builtin_amdgcn_mfma_f32_16x16x32_bf16(w1, bA[1][ks], acc[1][1], 0, 0, 0);
      }
      // epilogue: y at c = t*32 + f*16 + 4q + j, row = own row (r15)
      unsigned yw[2][2][2];
#pragma unroll
      for (int rt = 0; rt < 2; ++rt)
#pragma unroll
        for (int f = 0; f < 2; ++f) {
          float o0 = ssilu(acc[rt][f][0]), o1 = ssilu(acc[rt][f][1]);
          float o2 = ssilu(acc[rt][f][2]), o3 = ssilu(acc[rt][f][3]);
          if (isRes) {
            const unsigned p0 = xs[t][rt][f][0], p1 = xs[t][rt][f][1];
            o0 = (bf2f((unsigned short)(p0 & 0xffff)) + o0) * INV_SQRT2;
            o1 = (bf2f((unsigned short)(p0 >> 16)) + o1) * INV_SQRT2;
            o2 = (bf2f((unsigned short)(p1 & 0xffff)) + o2) * INV_SQRT2;
            o3 = (bf2f((unsigned short)(p1 >> 16)) + o3) * INV_SQRT2;
          }
          const unsigned h01 = (unsigned)f2bf(o0) | ((unsigned)f2bf(o1) << 16);
          const unsigned h23 = (unsigned)f2bf(o2) | ((unsigned)f2bf(o3) << 16);
          if (isS0 | isRes) { xs[t][rt][f][0] = h01; xs[t][rt][f][1] = h23; }
          yw[rt][f][0] = h01; yw[rt][f][1] = h23;
        }
      // rebuild next-stage B-frag slot t via 4-lane permutation:
      // b[rt][t] word w <- lane (2(q&1)+(w>>1))<<4|r15, its yw[rt][q>>1][w&1]
      if (s < 6) {
#pragma unroll
        for (int rt = 0; rt < 2; ++rt) {
          unsigned vA0 = __shfl(yw[rt][0][0], sA, 64);
          unsigned vB0 = __shfl(yw[rt][1][0], sA, 64);
          unsigned W0 = qh ? vB0 : vA0;
          unsigned vA1 = __shfl(yw[rt][0][1], sA, 64);
          unsigned vB1 = __shfl(yw[rt][1][1], sA, 64);
          unsigned W1 = qh ? vB1 : vA1;
          unsigned vA2 = __shfl(yw[rt][0][0], sB, 64);
          unsigned vB2 = __shfl(yw[rt][1][0], sB, 64);
          unsigned W2 = qh ? vB2 : vA2;
          unsigned vA3 = __shfl(yw[rt][0][1], sB, 64);
          unsigned vB3 = __shfl(yw[rt][1][1], sB, 64);
          unsigned W3 = qh ? vB3 : vA3;
          u32x4 pk = {W0, W1, W2, W3};
          bB[rt][t] = __builtin_bit_cast(bf16x8, pk);
        }
      }
    }
    if (s < 6) {
#pragma unroll
      for (int rt = 0; rt < 2; ++rt)
#pragma unroll
        for (int ks = 0; ks < 8; ++ks) bA[rt][ks] = bB[rt][ks];
    }
  }

  // ---- final: rbfw = rbf @ (Wf_rbf .* Wf_out);  F[row] = sum_c x6 .* rbfw ----
  bf16x8 rbfb[2];
#pragma unroll
  for (int rt = 0; rt < 2; ++rt) {
    bf16x8 t = {0, 0, 0, 0, 0, 0, 0, 0};
    if (q < 2) {
      const float* p = rbf + rg[rt] * 16 + q * 8;
      float4 v0 = *(const float4*)p;
      float4 v1 = *(const float4*)(p + 4);
      t[0] = (short)f2bf(v0.x); t[1] = (short)f2bf(v0.y);
      t[2] = (short)f2bf(v0.z); t[3] = (short)f2bf(v0.w);
      t[4] = (short)f2bf(v1.x); t[5] = (short)f2bf(v1.y);
      t[6] = (short)f2bf(v1.z); t[7] = (short)f2bf(v1.w);
    }
    rbfb[rt] = t;
  }
  // chunk 56 (W2F) done; tail re-stages (8 loads) may remain outstanding
  asm volatile("s_waitcnt vmcnt(8)" ::: "memory");
  __builtin_amdgcn_s_barrier();
  const char* wb2 = (const char*)wbuf;  // 56 & 3 == 0
  float psum[2] = {0.f, 0.f};
#pragma unroll
  for (int tt = 0; tt < 16; ++tt) {
    const int crow = tt * 16 + r15;
    bf16x8 w2 = *(const bf16x8*)(wb2 + crow * 64 + ((q * 16) ^ ((r15 & 3) << 4)));
#pragma unroll
    for (int rt = 0; rt < 2; ++rt) {
      f32x4 rw = __builtin_amdgcn_mfma_f32_16x16x32_bf16(w2, rbfb[rt], zf, 0, 0, 0);
      const unsigned p0 = xs[tt >> 1][rt][tt & 1][0];
      const unsigned p1 = xs[tt >> 1][rt][tt & 1][1];
      psum[rt] += bf2f((unsigned short)(p0 & 0xffff)) * rw[0]
                + bf2f((unsigned short)(p0 >> 16)) * rw[1]
                + bf2f((unsigned short)(p1 & 0xffff)) * rw[2]
                + bf2f((unsigned short)(p1 >> 16)) * rw[3];
    }
  }
#pragma unroll
  for (int rt = 0; rt < 2; ++rt) {
    psum[rt] += __shfl_xor(psum[rt], 16, 64);
    psum[rt] += __shfl_xor(psum[rt], 32, 64);
  }
  if (q == 0) {
#pragma unroll
    for (int rt = 0; rt < 2; ++rt) {
      const long long r = row0 + wrow + rt * 16 + r15;
      if (r < nE) Fout[r] = psum[rt];
    }
  }
}

// =====================================================================
// energy MLP: xE[25000][256] -> ssilu(@We_in[256x128]) -> 3 residual(128) -> @We_out
// (small: 196 blocks; unchanged from R3)
// =====================================================================
__global__ __launch_bounds__(256) void energy_kernel(
    const float* __restrict__ xE, const char* __restrict__ EWt0,
    const char* __restrict__ EWtR, const float* __restrict__ We_out,
    float* __restrict__ Eout, int nA) {
  __shared__ char xbuf[32768];  // [128][256B], swz key (row&15)<<4
  __shared__ char wbuf[16384];
  const int tid = threadIdx.x;
  const int lane = tid & 63, q = lane >> 4, r15 = lane & 15;
  const int wid = tid >> 6, wrow = wid * 32;
  const long long row0 = (long long)blockIdx.x * 128;
  const f32x4 zf = {0.f, 0.f, 0.f, 0.f};

  bf16x8 a[2][8];
  unsigned xs[4][2][2][2];

#pragma unroll
  for (int fr = 0; fr < 2; ++fr) {
#pragma unroll
    for (int ks = 0; ks < 8; ++ks) {
      long long rg = row0 + wrow + fr * 16 + r15;
      bf16x8 t = {0, 0, 0, 0, 0, 0, 0, 0};
      if (rg < nA) {
        const float* p = xE + rg * 256 + ks * 32 + q * 8;
        float4 v0 = *(const float4*)p;
        float4 v1 = *(const float4*)(p + 4);
        t[0] = (short)f2bf(v0.x); t[1] = (short)f2bf(v0.y);
        t[2] = (short)f2bf(v0.z); t[3] = (short)f2bf(v0.w);
        t[4] = (short)f2bf(v1.x); t[5] = (short)f2bf(v1.y);
        t[6] = (short)f2bf(v1.z); t[7] = (short)f2bf(v1.w);
      }
      a[fr][ks] = t;
    }
  }

  for (int s = 0; s < 7; ++s) {
    const int K2 = (s == 0) ? 512 : 256;  // bytes per weight row
    const int wchunk = 32 * K2;
    const int nld = wchunk >> 12;         // 4 or 2 16B-loads per thread
    const char* wsrc = (s == 0) ? EWt0 : (EWtR + (unsigned long long)(s - 1) * 32768);
    const int isS0 = (s == 0);
    const int isRes = (s >= 2) && ((s & 1) == 0);
#pragma unroll
    for (int c = 0; c < 4; ++c) {
      for (int i = 0; i < nld; ++i)
        gl16(wsrc + c * wchunk + i * 4096 + tid * 16, wbuf + i * 4096 + tid * 16);
      asm volatile("s_waitcnt vmcnt(0)" ::: "memory");
      __syncthreads();

      f32x4 acc[2][2] = {{zf, zf}, {zf, zf}};
      if (s == 0) {
#pragma unroll
        for (int ks = 0; ks < 8; ++ks) {
          const int kb = ks * 64 + q * 16;
          const int ci0 = r15, ci1 = 16 + r15;
          bf16x8 b0 = *(const bf16x8*)(wbuf + ci0 * 512 + (kb ^ ((ci0 & 15) << 4)));
          bf16x8 b1 = *(const bf16x8*)(wbuf + ci1 * 512 + (kb ^ ((ci1 & 15) << 4)));
          acc[0][0] = __builtin_amdgcn_mfma_f32_16x16x32_bf16(a[0][ks], b0, acc[0][0], 0, 0, 0);
          acc[1][0] = __builtin_amdgcn_mfma_f32_16x16x32_bf16(a[1][ks], b0, acc[1][0], 0, 0, 0);
          acc[0][1] = __builtin_amdgcn_mfma_f32_16x16x32_bf16(a[0][ks], b1, acc[0][1], 0, 0, 0);
          acc[1][1] = __builtin_amdgcn_mfma_f32_16x16x32_bf16(a[1][ks], b1, acc[1][1], 0, 0, 0);
        }
      } else {
#pragma unroll
        for (int ks = 0; ks < 4; ++ks) {
          const int kb = ks * 64 + q * 16;
          const int ci0 = r15, ci1 = 16 + r15;
          bf16x8 b0 = *(const bf16x8*)(wbuf + ci0 * 256 + (kb ^ ((ci0 & 15) << 4)));
          bf16x8 b1 = *(const bf16x8*)(wbuf + ci1 * 256 + (kb ^ ((ci1 & 15) << 4)));
          acc[0][0] = __builtin_amdgcn_mfma_f32_16x16x32_bf16(a[0][ks], b0, acc[0][0], 0, 0, 0);
          acc[1][0] = __builtin_amdgcn_mfma_f32_16x16x32_bf16(a[1][ks], b0, acc[1][0], 0, 0, 0);
          acc[0][1] = __builtin_amdgcn_mfma_f32_16x16x32_bf16(a[0][ks], b1, acc[0][1], 0, 0, 0);
          acc[1][1] = __builtin_amdgcn_mfma_f32_16x16x32_bf16(a[1][ks], b1, acc[1][1], 0, 0, 0);
        }
      }
#pragma unroll
      for (int fr = 0; fr < 2; ++fr) {
#pragma unroll
        for (int fc = 0; fc < 2; ++fc) {
          float o0 = ssilu(acc[fr][fc][0]), o1 = ssilu(acc[fr][fc][1]);
          float o2 = ssilu(acc[fr][fc][2]), o3 = ssilu(acc[fr][fc][3]);
          if (isRes) {
            const unsigned p0 = xs[c][fr][fc][0], p1 = xs[c][fr][fc][1];
            o0 = (bf2f((unsigned short)(p0 & 0xffff)) + o0) * INV_SQRT2;
            o1 = (bf2f((unsigned short)(p0 >> 16)) + o1) * INV_SQRT2;
            o2 = (bf2f((unsigned short)(p1 & 0xffff)) + o2) * INV_SQRT2;
            o3 = (bf2f((unsigned short)(p1 >> 16)) + o3) * INV_SQRT2;
          }
          const unsigned short h0 = f2bf(o0), h1 = f2bf(o1), h2 = f2bf(o2), h3 = f2bf(o3);
          if (isS0 | isRes) {
            xs[c][fr][fc][0] = (unsigned)h0 | ((unsigned)h1 << 16);
            xs[c][fr][fc][1] = (unsigned)h2 | ((unsigned)h3 << 16);
          }
          if (s < 6) {
            const int colb = (c * 32 + fc * 16 + r15) * 2;
            const int rb = wrow + fr * 16 + q * 4;
            *(unsigned short*)(xbuf + (rb + 0) * 256 + (colb ^ (((rb + 0) & 15) << 4))) = h0;
            *(unsigned short*)(xbuf + (rb + 1) * 256 + (colb ^ (((rb + 1) & 15) << 4))) = h1;
            *(unsigned short*)(xbuf + (rb + 2) * 256 + (colb ^ (((rb + 2) & 15) << 4))) = h2;
            *(unsigned short*)(xbuf + (rb + 3) * 256 + (colb ^ (((rb + 3) & 15) << 4))) = h3;
          }
        }
      }
      __syncthreads();
    }
    if (s < 6) {
#pragma unroll
      for (int fr = 0; fr < 2; ++fr) {
#pragma unroll
        for (int ks = 0; ks < 4; ++ks) {
          const int row = wrow + fr * 16 + r15;
          const int kb = ks * 64 + q * 16;
          a[fr][ks] = *(const bf16x8*)(xbuf + row * 256 + (kb ^ (r15 << 4)));
        }
      }
      __syncthreads();
    }
  }

  // final: E[row] = sum_c x[row,c] * We_out[c]
  float psum[2][4] = {{0.f, 0.f, 0.f, 0.f}, {0.f, 0.f, 0.f, 0.f}};
#pragma unroll
  for (int c = 0; c < 4; ++c) {
#pragma unroll
    for (int f = 0; f < 2; ++f) {
      const int col = c * 32 + f * 16 + r15;
      const float wo = We_out[col];
#pragma unroll
      for (int fr = 0; fr < 2; ++fr) {
        const unsigned p0 = xs[c][fr][f][0], p1 = xs[c][fr][f][1];
        psum[fr][0] += bf2f((unsigned short)(p0 & 0xffff)) * wo;
        psum[fr][1] += bf2f((unsigned short)(p0 >> 16)) * wo;
        psum[fr][2] += bf2f((unsigned short)(p1 & 0xffff)) * wo;
        psum[fr][3] += bf2f((unsigned short)(p1 >> 16)) * wo;
      }
    }
  }
#pragma unroll
  for (int off = 1; off < 16; off <<= 1) {
#pragma unroll
    for (int fr = 0; fr < 2; ++fr) {
#pragma unroll
      for (int j = 0; j < 4; ++j) psum[fr][j] += __shfl_xor(psum[fr][j], off, 64);
    }
  }
  if (r15 == 0) {
#pragma unroll
    for (int fr = 0; fr < 2; ++fr) {
#pragma unroll
      for (int j = 0; j < 4; ++j) {
        const long long rg = row0 + wrow + fr * 16 + q * 4 + j;
        if (rg < nA) Eout[rg] = psum[fr][j];
      }
    }
  }
}

// =====================================================================
extern "C" void kernel_launch(void* const* d_in, const int* in_sizes, int n_in,
                              void* d_out, int out_size, void* d_ws, size_t ws_size,
                              hipStream_t stream) {
  const float* m      = (const float*)d_in[1];
  const float* rbf    = (const float*)d_in[2];
  const int*   id_j   = (const int*)d_in[3];
  const float* We_rbf = (const float*)d_in[4];
  const float* We_in  = (const float*)d_in[5];
  const float* We_res = (const float*)d_in[6];
  const float* We_out = (const float*)d_in[7];
  const float* Wf_rbf = (const float*)d_in[8];
  const float* Wf_in  = (const float*)d_in[9];
  const float* Wf_res = (const float*)d_in[10];
  const float* Wf_out = (const float*)d_in[11];
  const int nA = in_sizes[0] / 128;   // 25000
  const int nE = in_sizes[1] / 256;   // 400000

  char* ws = (char*)d_ws;
  float* xE = (float*)(ws + XE_OFF);
  float* Eout = (float*)d_out;
  float* Fout = Eout + nA;

  prep_kernel<<<2368, 256, 0, stream>>>(We_rbf, We_in, We_res, Wf_rbf, Wf_in, Wf_res, Wf_out, ws);
  hipMemsetAsync(xE, 0, (size_t)nA * 256 * 4, stream);
  scatter_kernel<<<(nE + 127) / 128, 256, 0, stream>>>(m, rbf, id_j, ws + W2E_OFF, xE, nE);
  energy_kernel<<<(nA + 127) / 128, 256, 0, stream>>>(xE, ws + EWT0_OFF, ws + EWTR_OFF, We_out, Eout, nA);
  force_kernel<<<(nE + 127) / 128, 256, 0, stream>>>(m, rbf, ws + FWT_OFF, ws + W2F_OFF, Fout, nE);
}